// Round 12
// baseline (989.388 us; speedup 1.0000x reference)
//
#include <hip/hip_runtime.h>
#include <hip/hip_bf16.h>
#include <math.h>

#define D 64
#define RU 256
#define CHUNK 8
#define QSTRIDE 68
#define BIN_SHIFT 7          // 128 links per coarse bin
#define NSB 256              // setup blocks for histA/scatterC

typedef short bf16x8 __attribute__((ext_vector_type(8)));
typedef float f32x4 __attribute__((ext_vector_type(4)));

__device__ __forceinline__ float selu_f(float x) {
    return x > 0.0f ? 1.0507009873554805f * x
                    : 1.7580993408473766f * (__expf(x) - 1.0f);
}

__device__ __forceinline__ short f2bf_rtne(float x) {
    union { float f; unsigned u; } v; v.f = x;
    unsigned r = (v.u + 0x7FFFu + ((v.u >> 16) & 1u)) >> 16;
    return (short)r;
}
__device__ __forceinline__ float bf2f(short s) {
    union { float f; unsigned u; } v; v.u = ((unsigned)(unsigned short)s) << 16;
    return v.f;
}
__device__ __forceinline__ unsigned packpair(float a, float b) {
    float2 p; p.x = a; p.y = b;
    __hip_bfloat162 hb = __float22bfloat162_rn(p);
    return *(unsigned*)&hb;
}

__device__ __forceinline__ bf16x8 pack8(const float* v) {
    union { bf16x8 v; unsigned u[4]; } H;
#pragma unroll
    for (int j = 0; j < 4; ++j) H.u[j] = packpair(v[2 * j], v[2 * j + 1]);
    return H.v;
}

__device__ __forceinline__ void split_pack8(const float* v, bf16x8* hi, bf16x8* lo) {
    union { bf16x8 v; unsigned u[4]; } H, L;
#pragma unroll
    for (int j = 0; j < 4; ++j) {
        float2 p; p.x = v[2 * j]; p.y = v[2 * j + 1];
        __hip_bfloat162 hb = __float22bfloat162_rn(p);
        unsigned hu = *(unsigned*)&hb;
        H.u[j] = hu;
        union { unsigned u; float f; } e, o;
        e.u = hu << 16;
        o.u = hu & 0xffff0000u;
        L.u[j] = packpair(p.x - e.f, p.y - o.f);
    }
    *hi = H.v; *lo = L.v;
}

// ================= weight prep (once): split + transpose to [n][k] bf16 ======
__global__ __launch_bounds__(256) void w_prep_kernel(
    const float* __restrict__ W_msg, const float* __restrict__ W_gcn,
    unsigned short* __restrict__ WtH, unsigned short* __restrict__ WtL,
    unsigned short* __restrict__ WbH, unsigned short* __restrict__ WbL,
    unsigned short* __restrict__ GT)
{
    const int i = blockIdx.x * 256 + threadIdx.x;   // 4096 = 64x64
    const int n = i >> 6, k = i & 63;
    const float wt = W_msg[k * 64 + n];
    const short th = f2bf_rtne(wt);
    WtH[n * 64 + k] = (unsigned short)th;
    WtL[n * 64 + k] = (unsigned short)f2bf_rtne(wt - bf2f(th));
    const float wb = W_msg[(64 + k) * 64 + n];
    const short bh = f2bf_rtne(wb);
    WbH[n * 64 + k] = (unsigned short)bh;
    WbL[n * 64 + k] = (unsigned short)f2bf_rtne(wb - bf2f(bh));
    GT[n * 64 + k] = (unsigned short)f2bf_rtne(W_gcn[k * 64 + n]);
}

// ================= atomic-free CSR build (r11, unchanged) =================

__global__ __launch_bounds__(256) void histA_kernel(
    const int* __restrict__ second, int* __restrict__ ghist,
    int n_edges, int nbins)
{
    __shared__ int lhist[1024];
    for (int i = threadIdx.x; i < nbins; i += 256) lhist[i] = 0;
    __syncthreads();
    const int per = (n_edges + gridDim.x - 1) / gridDim.x;
    const int e0 = blockIdx.x * per;
    const int e1 = min(e0 + per, n_edges);
    for (int e = e0 + threadIdx.x; e < e1; e += 256)
        atomicAdd(&lhist[second[e] >> BIN_SHIFT], 1);
    __syncthreads();
    for (int i = threadIdx.x; i < nbins; i += 256)
        ghist[i * gridDim.x + blockIdx.x] = lhist[i];
}

__global__ __launch_bounds__(1024) void scan8_kernel(int* __restrict__ data, int n)
{
    __shared__ int wsum[16], woff[16];
    __shared__ int s_total, s_carry;
    const int tid = threadIdx.x, wave = tid >> 6, lane = tid & 63;
    if (tid == 0) s_carry = 0;
    __syncthreads();
    for (int base = 0; base < n; base += 8192) {
        const int i0 = base + tid * 8;
        int x[8];
#pragma unroll
        for (int k = 0; k < 8; ++k) x[k] = 0;
        if (i0 + 8 <= n) {
            const int4 a = *(const int4*)(data + i0);
            const int4 b = *(const int4*)(data + i0 + 4);
            x[0] = a.x; x[1] = a.y; x[2] = a.z; x[3] = a.w;
            x[4] = b.x; x[5] = b.y; x[6] = b.z; x[7] = b.w;
        } else {
#pragma unroll
            for (int k = 0; k < 8; ++k) if (i0 + k < n) x[k] = data[i0 + k];
        }
        int tot = 0;
#pragma unroll
        for (int k = 0; k < 8; ++k) tot += x[k];
        int v = tot;
#pragma unroll
        for (int off = 1; off < 64; off <<= 1) {
            int t = __shfl_up(v, off, 64);
            if (lane >= off) v += t;
        }
        if (lane == 63) wsum[wave] = v;
        __syncthreads();
        if (wave == 0) {
            int s = (lane < 16) ? wsum[lane] : 0;
#pragma unroll
            for (int off = 1; off < 16; off <<= 1) {
                int t = __shfl_up(s, off, 64);
                if (lane >= off) s += t;
            }
            if (lane < 16) woff[lane] = s - wsum[lane];
            if (lane == 15) s_total = s;
        }
        __syncthreads();
        int pre = s_carry + woff[wave] + (v - tot);
#pragma unroll
        for (int k = 0; k < 8; ++k) {
            if (i0 + k < n) data[i0 + k] = pre;
            pre += x[k];
        }
        __syncthreads();
        if (tid == 0) s_carry += s_total;
        __syncthreads();
    }
}

__global__ __launch_bounds__(256) void scatterC_kernel(
    const int* __restrict__ first, const int* __restrict__ second,
    const int* __restrict__ offs, int* __restrict__ tmp_first,
    int* __restrict__ tmp_sec, int n_edges, int nbins)
{
    __shared__ int lcur[1024];
    for (int i = threadIdx.x; i < nbins; i += 256)
        lcur[i] = offs[i * gridDim.x + blockIdx.x];
    __syncthreads();
    const int per = (n_edges + gridDim.x - 1) / gridDim.x;
    const int e0 = blockIdx.x * per;
    const int e1 = min(e0 + per, n_edges);
    for (int e = e0 + threadIdx.x; e < e1; e += 256) {
        const int s = second[e];
        const int pos = atomicAdd(&lcur[s >> BIN_SHIFT], 1);
        tmp_first[pos] = first[e];
        tmp_sec[pos] = s;
    }
}

__global__ __launch_bounds__(256) void binsortD_kernel(
    const int* __restrict__ tmp_first, const int* __restrict__ tmp_sec,
    const int* __restrict__ offs, int* __restrict__ sfirst,
    int* __restrict__ row_ptr, int n_edges, int n_links, int nbins)
{
    __shared__ int ldeg[128];
    __shared__ int lpre[128];
    __shared__ int lcur[128];
    const int b = blockIdx.x;
    const int tid = threadIdx.x;
    const int lbase = b << BIN_SHIFT;
    const int nl = min(128, n_links - lbase);
    const int eb = offs[b * NSB];
    const int ee = (b + 1 < nbins) ? offs[(b + 1) * NSB] : n_edges;

    if (tid < 128) ldeg[tid] = 0;
    __syncthreads();
    for (int e = eb + tid; e < ee; e += 256)
        atomicAdd(&ldeg[tmp_sec[e] - lbase], 1);
    __syncthreads();
    if (tid < 64) {
        const int d0 = ldeg[tid], d1 = ldeg[64 + tid];
        int p0 = d0, p1 = d1;
#pragma unroll
        for (int off = 1; off < 64; off <<= 1) {
            const int t0 = __shfl_up(p0, off, 64);
            const int t1 = __shfl_up(p1, off, 64);
            if (tid >= off) { p0 += t0; p1 += t1; }
        }
        const int tot0 = __shfl(p0, 63, 64);
        lpre[tid] = p0 - d0;
        lpre[64 + tid] = tot0 + p1 - d1;
    }
    __syncthreads();
    if (tid < nl) row_ptr[lbase + tid] = eb + lpre[tid];
    if (b == nbins - 1 && tid == 0) row_ptr[n_links] = n_edges;
    if (tid < 128) lcur[tid] = lpre[tid];
    __syncthreads();
    for (int e = eb + tid; e < ee; e += 256) {
        const int pos = eb + atomicAdd(&lcur[tmp_sec[e] - lbase], 1);
        sfirst[pos] = tmp_first[e];
    }
    if (b == 0)
        for (int i = tid; i < 64; i += 256) sfirst[n_edges + i] = 0;  // pipeline pad
}

__global__ __launch_bounds__(256) void growfind_kernel(
    const int* __restrict__ gid, int* __restrict__ grow, int n_links, int G)
{
    const int g = blockIdx.x * blockDim.x + threadIdx.x;
    if (g > G) return;
    if (g == G) { grow[G] = n_links; return; }
    int lo = 0, hi = n_links;
    while (lo < hi) {
        const int mid = (lo + hi) >> 1;
        if (gid[mid] < g) lo = mid + 1; else hi = mid;
    }
    grow[g] = lo;
}

// ================= pq_init: P̂,Q̂ from states_action (once) =================
// P̂ = bf16(state @ Wtop); Q̂ = bf16(state @ Wbot + b_msg). 3-term split MFMA.
__global__ __launch_bounds__(256) void pq_init_kernel(
    const float* __restrict__ state,
    const unsigned short* __restrict__ WtH, const unsigned short* __restrict__ WtL,
    const unsigned short* __restrict__ WbH, const unsigned short* __restrict__ WbL,
    const float* __restrict__ b_msg,
    unsigned short* __restrict__ P, unsigned short* __restrict__ Q, int n_links)
{
    __shared__ float ct[4][16 * QSTRIDE];
    const int tid = threadIdx.x;
    const int wave = tid >> 6;
    const int lane = tid & 63;
    const int m = lane & 15;
    const int qd = lane >> 4;

    const int base = blockIdx.x * 64 + wave * 16;
    if (base >= n_links) return;

    const int l = base + m;
    float xv[16];
    if (l < n_links) {
        const float4* Sr = (const float4*)(state + (size_t)l * D);
        *(float4*)&xv[0]  = Sr[qd * 2];
        *(float4*)&xv[4]  = Sr[qd * 2 + 1];
        *(float4*)&xv[8]  = Sr[8 + qd * 2];
        *(float4*)&xv[12] = Sr[9 + qd * 2];
    } else {
#pragma unroll
        for (int i = 0; i < 16; ++i) xv[i] = 0.0f;
    }
    bf16x8 Ah[2], Al[2];
    split_pack8(&xv[0], &Ah[0], &Al[0]);
    split_pack8(&xv[8], &Ah[1], &Al[1]);

    float bmsgC[4];
#pragma unroll
    for (int jt = 0; jt < 4; ++jt) bmsgC[jt] = b_msg[jt * 16 + m];

#pragma unroll
    for (int mat = 0; mat < 2; ++mat) {
        const unsigned short* WH = mat ? WbH : WtH;
        const unsigned short* WL = mat ? WbL : WtL;
        f32x4 acc[4];
#pragma unroll
        for (int jt = 0; jt < 4; ++jt) {
            const float b = mat ? bmsgC[jt] : 0.0f;
            acc[jt] = (f32x4){b, b, b, b};
        }
#pragma unroll
        for (int ks = 0; ks < 2; ++ks)
#pragma unroll
            for (int jt = 0; jt < 4; ++jt) {
                const bf16x8 bh = *(const bf16x8*)(WH + (size_t)(jt * 16 + m) * 64 + ks * 32 + qd * 8);
                const bf16x8 bl = *(const bf16x8*)(WL + (size_t)(jt * 16 + m) * 64 + ks * 32 + qd * 8);
                acc[jt] = __builtin_amdgcn_mfma_f32_16x16x32_bf16(Ah[ks], bh, acc[jt], 0, 0, 0);
                acc[jt] = __builtin_amdgcn_mfma_f32_16x16x32_bf16(Ah[ks], bl, acc[jt], 0, 0, 0);
                acc[jt] = __builtin_amdgcn_mfma_f32_16x16x32_bf16(Al[ks], bh, acc[jt], 0, 0, 0);
            }
        // C-layout -> LDS rows -> packed bf16 store
#pragma unroll
        for (int r = 0; r < 4; ++r)
#pragma unroll
            for (int jt = 0; jt < 4; ++jt)
                ct[wave][(qd * 4 + r) * QSTRIDE + jt * 16 + m] = acc[jt][r];
        {
            const int row = lane >> 2, c = lane & 3;   // 16 rows x 16-feature blocks
            const int lr = base + row;
            if (lr < n_links) {
                float4 a = *(float4*)&ct[wave][row * QSTRIDE + c * 16];
                float4 b = *(float4*)&ct[wave][row * QSTRIDE + c * 16 + 4];
                float4 cc = *(float4*)&ct[wave][row * QSTRIDE + c * 16 + 8];
                float4 d = *(float4*)&ct[wave][row * QSTRIDE + c * 16 + 12];
                uint4 o0, o1;
                o0.x = packpair(a.x, a.y); o0.y = packpair(a.z, a.w);
                o0.z = packpair(b.x, b.y); o0.w = packpair(b.z, b.w);
                o1.x = packpair(cc.x, cc.y); o1.y = packpair(cc.z, cc.w);
                o1.z = packpair(d.x, d.y); o1.w = packpair(d.z, d.w);
                unsigned short* dst = (mat ? Q : P) + (size_t)lr * D + c * 16;
                *(uint4*)dst = o0;
                *(uint4*)(dst + 8) = o1;
            }
        }
    }
}

// ================= fused edge kernel =================
// Main loop: gather P̂, qb from staged Q̂, selu, MFMA GCN (bias as C), relu-sum.
// Epilogue (produce_pq): compute next-iteration P̂,Q̂ for own links from the
// S rows captured in LDS (3-term split MFMA, prepped weights). S written to
// global only when write_s (last iteration).
// NOTE: no min-waves clause — (256,5) caused a full spill (r8).
__global__ __launch_bounds__(256) void edge_link_kernel(
    const unsigned short* __restrict__ Pin, const unsigned short* __restrict__ Qin,
    const int* __restrict__ sfirst, const int* __restrict__ row_ptr,
    const unsigned short* __restrict__ GT,
    const unsigned short* __restrict__ WtH, const unsigned short* __restrict__ WtL,
    const unsigned short* __restrict__ WbH, const unsigned short* __restrict__ WbL,
    const float* __restrict__ b_msg, const float* __restrict__ b_gcn,
    unsigned short* __restrict__ Pout, unsigned short* __restrict__ Qout,
    float* __restrict__ S, int n_links, int produce_pq, int write_s)
{
    __shared__ float qt[4][CHUNK * QSTRIDE];      // S-row capture + C scratch
    __shared__ unsigned qbuf[4][CHUNK * 32];      // Q̂ chunk (bf16)
    const int tid = threadIdx.x;
    const int wave = tid >> 6;
    const int lane = tid & 63;
    const int m = lane & 15;
    const int qd = lane >> 4;

    const int l0 = (blockIdx.x * 4 + wave) * CHUNK;
    if (l0 >= n_links) return;
    const int l1 = min(l0 + CHUNK, n_links);
    const int nl = l1 - l0;

    // stage Q̂ chunk into LDS (1 KB/wave, coalesced)
    {
        const int li = lane >> 3, blk = lane & 7;
        const int l = l0 + li;
        uint4 v = make_uint4(0, 0, 0, 0);
        if (l < n_links)
            v = *(const uint4*)(Qin + (size_t)l * D + blk * 8);
        *(uint4*)&qbuf[wave][li * 32 + blk * 4] = v;
    }
    if (produce_pq)
        for (int i = lane; i < CHUNK * QSTRIDE; i += 64) qt[wave][i] = 0.0f;

    // W_gcn B frags (plain bf16, prepped): direct 16B loads, no conversion
    bf16x8 Gh[2][4];
#pragma unroll
    for (int ks = 0; ks < 2; ++ks)
#pragma unroll
        for (int jt = 0; jt < 4; ++jt)
            Gh[ks][jt] = *(const bf16x8*)(GT + (size_t)(jt * 16 + m) * 64 + ks * 32 + qd * 8);
    f32x4 biasvec[4];
    float rb[4], bmsgC[4];
#pragma unroll
    for (int jt = 0; jt < 4; ++jt) {
        const float b = b_gcn[jt * 16 + m];
        biasvec[jt] = (f32x4){b, b, b, b};
        rb[jt] = fmaxf(b, 0.0f);
        bmsgC[jt] = b_msg[jt * 16 + m];
    }

    // per-chunk row_ptr table in one lane-vector register
    const int rpv = row_ptr[l0 + min(lane, nl)];
#define RP(i) __shfl(rpv, (i), 64)

    int li0 = 0;
    while (li0 < nl && RP(li0 + 1) == RP(li0)) {
        if (write_s) S[(size_t)(l0 + li0) * D + lane] = 0.0f;
        ++li0;
    }
    if (li0 < nl) {
        int eo0 = RP(li0), ee0 = RP(li0 + 1);

        auto advance = [&](int& li, int& eo, int& ee, bool& v) {
            if (!v) return;
            eo += 16;
            if (eo < ee) return;
            int i = li + 1;
            while (i < nl) {
                const int a = RP(i), b = RP(i + 1);
                if (b > a) { li = i; eo = a; ee = b; return; }
                if (write_s) S[(size_t)(l0 + i) * D + lane] = 0.0f;
                ++i;
            }
            v = false;
        };

        int li1 = li0, eo1 = eo0, ee1 = ee0; bool v1 = true;
        advance(li1, eo1, ee1, v1);
        int li2 = li1, eo2 = eo1, ee2 = ee1; bool v2 = v1;
        advance(li2, eo2, ee2, v2);

        const int sf0 = sfirst[eo0 + m];
        int sf1 = sfirst[eo1 + m];
        const unsigned short* Pr0 = Pin + (size_t)sf0 * D;
        bf16x8 p00 = *(const bf16x8*)(Pr0 + qd * 8);
        bf16x8 p01 = *(const bf16x8*)(Pr0 + 32 + qd * 8);

        float qb[16];
        int qli = -1;
        float rsum[4] = {0.f, 0.f, 0.f, 0.f};

        while (true) {
            const int sf2 = sfirst[eo2 + m];
            const unsigned short* Pr1 = Pin + (size_t)sf1 * D;
            const bf16x8 p10 = *(const bf16x8*)(Pr1 + qd * 8);
            const bf16x8 p11 = *(const bf16x8*)(Pr1 + 32 + qd * 8);

            if (li0 != qli) {
                qli = li0;
                const bf16x8 q0 = *(const bf16x8*)&qbuf[wave][li0 * 32 + qd * 4];
                const bf16x8 q1 = *(const bf16x8*)&qbuf[wave][li0 * 32 + 16 + qd * 4];
#pragma unroll
                for (int i = 0; i < 8; ++i) {
                    qb[i] = bf2f(q0[i]);
                    qb[8 + i] = bf2f(q1[i]);
                }
            }
            const bool ev = (eo0 + m < ee0);
            float msg[16];
#pragma unroll
            for (int i = 0; i < 8; ++i) {
                msg[i]     = ev ? selu_f(bf2f(p00[i]) + qb[i])     : 0.0f;
                msg[8 + i] = ev ? selu_f(bf2f(p01[i]) + qb[8 + i]) : 0.0f;
            }
            bf16x8 Ah0 = pack8(&msg[0]);
            bf16x8 Ah1 = pack8(&msg[8]);

            f32x4 acc[4];
#pragma unroll
            for (int jt = 0; jt < 4; ++jt) {
                acc[jt] = __builtin_amdgcn_mfma_f32_16x16x32_bf16(Ah0, Gh[0][jt], biasvec[jt], 0, 0, 0);
                acc[jt] = __builtin_amdgcn_mfma_f32_16x16x32_bf16(Ah1, Gh[1][jt], acc[jt], 0, 0, 0);
            }
#pragma unroll
            for (int jt = 0; jt < 4; ++jt)
#pragma unroll
                for (int r = 0; r < 4; ++r)
                    rsum[jt] += fmaxf(acc[jt][r], 0.0f);

            const int over = eo0 + qd * 4 + 4 - ee0;
            const float cnt = (float)max(0, min(4, over));
#pragma unroll
            for (int jt = 0; jt < 4; ++jt)
                rsum[jt] -= rb[jt] * cnt;

            if (eo0 + 16 >= ee0) {   // last tile of link li0
#pragma unroll
                for (int jt = 0; jt < 4; ++jt) {
                    rsum[jt] += __shfl_xor(rsum[jt], 16, 64);
                    rsum[jt] += __shfl_xor(rsum[jt], 32, 64);
                }
                const float outv = (qd == 0) ? rsum[0] : (qd == 1) ? rsum[1]
                                 : (qd == 2) ? rsum[2] : rsum[3];
                if (produce_pq) qt[wave][li0 * QSTRIDE + lane] = outv;
                if (write_s)    S[(size_t)(l0 + li0) * D + lane] = outv;
#pragma unroll
                for (int jt = 0; jt < 4; ++jt) rsum[jt] = 0.0f;
            }

            if (!v1) break;
            li0 = li1; eo0 = eo1; ee0 = ee1;
            li1 = li2; eo1 = eo2; ee1 = ee2; v1 = v2;
            advance(li2, eo2, ee2, v2);
            p00 = p10; p01 = p11;
            sf1 = sf2;
        }
    }

    // ---- epilogue: produce P̂,Q̂ for next iteration from captured S rows ----
    if (produce_pq) {
        float xv[16];
        if (m < CHUNK) {
            *(float4*)&xv[0]  = *(float4*)&qt[wave][m * QSTRIDE + qd * 8];
            *(float4*)&xv[4]  = *(float4*)&qt[wave][m * QSTRIDE + qd * 8 + 4];
            *(float4*)&xv[8]  = *(float4*)&qt[wave][m * QSTRIDE + 32 + qd * 8];
            *(float4*)&xv[12] = *(float4*)&qt[wave][m * QSTRIDE + 32 + qd * 8 + 4];
        } else {
#pragma unroll
            for (int i = 0; i < 16; ++i) xv[i] = 0.0f;
        }
        bf16x8 Ah[2], Al[2];
        split_pack8(&xv[0], &Ah[0], &Al[0]);
        split_pack8(&xv[8], &Ah[1], &Al[1]);

#pragma unroll
        for (int mat = 0; mat < 2; ++mat) {
            const unsigned short* WH = mat ? WbH : WtH;
            const unsigned short* WL = mat ? WbL : WtL;
            f32x4 acc[4];
#pragma unroll
            for (int jt = 0; jt < 4; ++jt) {
                const float b = mat ? bmsgC[jt] : 0.0f;
                acc[jt] = (f32x4){b, b, b, b};
            }
#pragma unroll
            for (int ks = 0; ks < 2; ++ks)
#pragma unroll
                for (int jt = 0; jt < 4; ++jt) {
                    const bf16x8 bh = *(const bf16x8*)(WH + (size_t)(jt * 16 + m) * 64 + ks * 32 + qd * 8);
                    const bf16x8 bl = *(const bf16x8*)(WL + (size_t)(jt * 16 + m) * 64 + ks * 32 + qd * 8);
                    acc[jt] = __builtin_amdgcn_mfma_f32_16x16x32_bf16(Ah[ks], bh, acc[jt], 0, 0, 0);
                    acc[jt] = __builtin_amdgcn_mfma_f32_16x16x32_bf16(Ah[ks], bl, acc[jt], 0, 0, 0);
                    acc[jt] = __builtin_amdgcn_mfma_f32_16x16x32_bf16(Al[ks], bh, acc[jt], 0, 0, 0);
                }
            // C-layout -> LDS rows (only rows < CHUNK are real links)
#pragma unroll
            for (int r = 0; r < 4; ++r) {
                const int row = qd * 4 + r;
                if (row < CHUNK)
#pragma unroll
                    for (int jt = 0; jt < 4; ++jt)
                        qt[wave][row * QSTRIDE + jt * 16 + m] = acc[jt][r];
            }
            // pack + coalesced bf16 store
            {
                const int row = lane >> 3, c = lane & 7;
                const int lr = l0 + row;
                if (row < nl) {
                    float4 a = *(float4*)&qt[wave][row * QSTRIDE + c * 8];
                    float4 b = *(float4*)&qt[wave][row * QSTRIDE + c * 8 + 4];
                    uint4 o;
                    o.x = packpair(a.x, a.y); o.y = packpair(a.z, a.w);
                    o.z = packpair(b.x, b.y); o.w = packpair(b.z, b.w);
                    unsigned short* dst = (mat ? Qout : Pout) + (size_t)lr * D + c * 8;
                    *(uint4*)dst = o;
                }
            }
        }
    }
#undef RP
}

// ---------------- readout: parallel segment-sum + tiny MLP ----------------
__global__ __launch_bounds__(256) void gsum8_kernel(
    const float* __restrict__ S, const int* __restrict__ grow,
    float* __restrict__ gemb)
{
    __shared__ float red[4][64];
    const int g = blockIdx.x >> 3;
    const int slice = blockIdx.x & 7;
    const int slot = threadIdx.x >> 6;
    const int j = threadIdx.x & 63;
    const int ls = grow[g], le = grow[g + 1];
    float acc = 0.0f;
    for (int l = ls + slice * 4 + slot; l < le; l += 32)
        acc += S[(size_t)l * D + j];
    red[slot][j] = acc;
    __syncthreads();
    if (slot == 0)
        atomicAdd(&gemb[g * D + j], red[0][j] + red[1][j] + red[2][j] + red[3][j]);
}

__global__ __launch_bounds__(256) void mlp_kernel(
    const float* __restrict__ gemb,
    const float* __restrict__ W_r1, const float* __restrict__ b_r1,
    const float* __restrict__ W_r2, const float* __restrict__ b_r2,
    const float* __restrict__ W_r3, const float* __restrict__ b_r3,
    float* __restrict__ out)
{
    __shared__ float gl[64];
    __shared__ float row1[RU];
    __shared__ float row2[RU];
    __shared__ float fin[4];
    const int g = blockIdx.x;
    const int tid = threadIdx.x;
    const int slot = tid >> 6;
    const int lane = tid & 63;

    if (tid < 64) gl[tid] = gemb[g * D + tid];
    __syncthreads();

    float a1 = b_r1[tid];
#pragma unroll 8
    for (int k = 0; k < 64; ++k) a1 += gl[k] * W_r1[k * RU + tid];
    row1[tid] = selu_f(a1);
    __syncthreads();

    float a2 = b_r2[tid];
#pragma unroll 8
    for (int k = 0; k < RU; ++k) a2 += row1[k] * W_r2[k * RU + tid];
    row2[tid] = selu_f(a2);
    __syncthreads();

    float p = row2[tid] * W_r3[tid];
#pragma unroll
    for (int off = 32; off >= 1; off >>= 1)
        p += __shfl_down(p, off, 64);
    if (lane == 0) fin[slot] = p;
    __syncthreads();
    if (tid == 0)
        out[g] = fin[0] + fin[1] + fin[2] + fin[3] + b_r3[0];
}

extern "C" void kernel_launch(void* const* d_in, const int* in_sizes, int n_in,
                              void* d_out, int out_size, void* d_ws, size_t ws_size,
                              hipStream_t stream)
{
    const float* states_action = (const float*)d_in[0];
    const float* W_msg = (const float*)d_in[1];
    const float* b_msg = (const float*)d_in[2];
    const float* W_gcn = (const float*)d_in[3];
    const float* b_gcn = (const float*)d_in[4];
    const float* W_r1 = (const float*)d_in[5];
    const float* b_r1 = (const float*)d_in[6];
    const float* W_r2 = (const float*)d_in[7];
    const float* b_r2 = (const float*)d_in[8];
    const float* W_r3 = (const float*)d_in[9];
    const float* b_r3 = (const float*)d_in[10];
    const int* gid = (const int*)d_in[11];
    const int* first = (const int*)d_in[12];
    const int* second = (const int*)d_in[13];

    const int n_links = in_sizes[0] / D;     // 100000
    const int n_edges = in_sizes[12];        // 1600000
    const int G = out_size;                  // 256
    const int nbins = (n_links + 127) >> BIN_SHIFT;   // 782

    char* ws2 = (char*)d_ws;
    auto alloc = [&](size_t bytes) {
        char* p = ws2; ws2 += (bytes + 63) & ~(size_t)63; return p;
    };
    float* S = (float*)alloc((size_t)n_links * D * sizeof(float));         // 25.6 MB
    unsigned short* P0 = (unsigned short*)alloc((size_t)n_links * D * 2);  // 12.8 MB
    unsigned short* Q0 = (unsigned short*)alloc((size_t)n_links * D * 2);
    unsigned short* P1 = (unsigned short*)alloc((size_t)n_links * D * 2);
    unsigned short* Q1 = (unsigned short*)alloc((size_t)n_links * D * 2);
    float* gemb = (float*)alloc((size_t)G * D * sizeof(float));
    int* row_ptr = (int*)alloc((size_t)(n_links + 1) * sizeof(int));
    int* grow = (int*)alloc((size_t)(G + 1) * sizeof(int));
    int* ghist = (int*)alloc((size_t)nbins * NSB * sizeof(int));
    int* tmp_first = (int*)alloc((size_t)n_edges * sizeof(int));
    int* tmp_sec = (int*)alloc((size_t)n_edges * sizeof(int));
    int* sfirst = (int*)alloc((size_t)(n_edges + 64) * sizeof(int));
    unsigned short* WtH = (unsigned short*)alloc(64 * 64 * 2);
    unsigned short* WtL = (unsigned short*)alloc(64 * 64 * 2);
    unsigned short* WbH = (unsigned short*)alloc(64 * 64 * 2);
    unsigned short* WbL = (unsigned short*)alloc(64 * 64 * 2);
    unsigned short* GT = (unsigned short*)alloc(64 * 64 * 2);

    // ---- weight prep + atomic-free CSR build ----
    hipMemsetAsync(gemb, 0, (size_t)G * D * sizeof(float), stream);
    w_prep_kernel<<<16, 256, 0, stream>>>(W_msg, W_gcn, WtH, WtL, WbH, WbL, GT);
    histA_kernel<<<NSB, 256, 0, stream>>>(second, ghist, n_edges, nbins);
    scan8_kernel<<<1, 1024, 0, stream>>>(ghist, nbins * NSB);
    scatterC_kernel<<<NSB, 256, 0, stream>>>(first, second, ghist,
                                             tmp_first, tmp_sec, n_edges, nbins);
    binsortD_kernel<<<nbins, 256, 0, stream>>>(tmp_first, tmp_sec, ghist,
                                               sfirst, row_ptr, n_edges, n_links, nbins);
    growfind_kernel<<<2, 256, 0, stream>>>(gid, grow, n_links, G);

    // ---- initial P̂,Q̂ from input state ----
    const int init_blocks = (n_links + 63) / 64;
    pq_init_kernel<<<init_blocks, 256, 0, stream>>>(states_action, WtH, WtL, WbH, WbL,
                                                    b_msg, P0, Q0, n_links);

    // ---- T = 4 fused message-passing iterations (P̂,Q̂ double-buffered) ----
    const int edge_blocks = (n_links + 4 * CHUNK - 1) / (4 * CHUNK);  // 3125
    unsigned short* Pbuf[2] = {P0, P1};
    unsigned short* Qbuf[2] = {Q0, Q1};
    for (int t = 0; t < 4; ++t) {
        const int in = t & 1 ? 1 : 0;     // 0,1,0,1
        const int outb = 1 - in;
        const int produce = (t < 3) ? 1 : 0;
        const int write_s = (t == 3) ? 1 : 0;
        edge_link_kernel<<<edge_blocks, 256, 0, stream>>>(
            Pbuf[in], Qbuf[in], sfirst, row_ptr, GT,
            WtH, WtL, WbH, WbL, b_msg, b_gcn,
            Pbuf[outb], Qbuf[outb], S, n_links, produce, write_s);
    }

    // ---- readout ----
    gsum8_kernel<<<G * 8, 256, 0, stream>>>(S, grow, gemb);
    mlp_kernel<<<G, 256, 0, stream>>>(gemb, W_r1, b_r1, W_r2, b_r2,
                                      W_r3, b_r3, (float*)d_out);
}

// Round 13
// 862.478 us; speedup vs baseline: 1.1471x; 1.1471x over previous
//
#include <hip/hip_runtime.h>
#include <hip/hip_bf16.h>
#include <math.h>

#define D 64
#define RU 256
#define CHUNK 8
#define QSTRIDE 68
#define BIN_SHIFT 7          // 128 links per coarse bin
#define NSB 256              // setup blocks for histA/scatterC

typedef short bf16x8 __attribute__((ext_vector_type(8)));
typedef float f32x4 __attribute__((ext_vector_type(4)));

__device__ __forceinline__ float selu_f(float x) {
    return x > 0.0f ? 1.0507009873554805f * x
                    : 1.7580993408473766f * (__expf(x) - 1.0f);
}

__device__ __forceinline__ short f2bf_rtne(float x) {
    union { float f; unsigned u; } v; v.f = x;
    unsigned r = (v.u + 0x7FFFu + ((v.u >> 16) & 1u)) >> 16;
    return (short)r;
}
__device__ __forceinline__ float bf2f(short s) {
    union { float f; unsigned u; } v; v.u = ((unsigned)(unsigned short)s) << 16;
    return v.f;
}
__device__ __forceinline__ unsigned packpair(float a, float b) {
    float2 p; p.x = a; p.y = b;
    __hip_bfloat162 hb = __float22bfloat162_rn(p);
    return *(unsigned*)&hb;
}

__device__ __forceinline__ bf16x8 pack8(const float* v) {
    union { bf16x8 v; unsigned u[4]; } H;
#pragma unroll
    for (int j = 0; j < 4; ++j) H.u[j] = packpair(v[2 * j], v[2 * j + 1]);
    return H.v;
}

__device__ __forceinline__ void split_pack8(const float* v, bf16x8* hi, bf16x8* lo) {
    union { bf16x8 v; unsigned u[4]; } H, L;
#pragma unroll
    for (int j = 0; j < 4; ++j) {
        float2 p; p.x = v[2 * j]; p.y = v[2 * j + 1];
        __hip_bfloat162 hb = __float22bfloat162_rn(p);
        unsigned hu = *(unsigned*)&hb;
        H.u[j] = hu;
        union { unsigned u; float f; } e, o;
        e.u = hu << 16;
        o.u = hu & 0xffff0000u;
        L.u[j] = packpair(p.x - e.f, p.y - o.f);
    }
    *hi = H.v; *lo = L.v;
}

// ================= weight prep (once): split + transpose to [n][k] bf16 ======
__global__ __launch_bounds__(256) void w_prep_kernel(
    const float* __restrict__ W_msg, const float* __restrict__ W_gcn,
    unsigned short* __restrict__ WtH, unsigned short* __restrict__ WtL,
    unsigned short* __restrict__ WbH, unsigned short* __restrict__ WbL,
    unsigned short* __restrict__ GT)
{
    const int i = blockIdx.x * 256 + threadIdx.x;   // 4096 = 64x64
    const int n = i >> 6, k = i & 63;
    const float wt = W_msg[k * 64 + n];
    const short th = f2bf_rtne(wt);
    WtH[n * 64 + k] = (unsigned short)th;
    WtL[n * 64 + k] = (unsigned short)f2bf_rtne(wt - bf2f(th));
    const float wb = W_msg[(64 + k) * 64 + n];
    const short bh = f2bf_rtne(wb);
    WbH[n * 64 + k] = (unsigned short)bh;
    WbL[n * 64 + k] = (unsigned short)f2bf_rtne(wb - bf2f(bh));
    GT[n * 64 + k] = (unsigned short)f2bf_rtne(W_gcn[k * 64 + n]);
}

// ================= atomic-free CSR build (r11, unchanged) =================

__global__ __launch_bounds__(256) void histA_kernel(
    const int* __restrict__ second, int* __restrict__ ghist,
    int n_edges, int nbins)
{
    __shared__ int lhist[1024];
    for (int i = threadIdx.x; i < nbins; i += 256) lhist[i] = 0;
    __syncthreads();
    const int per = (n_edges + gridDim.x - 1) / gridDim.x;
    const int e0 = blockIdx.x * per;
    const int e1 = min(e0 + per, n_edges);
    for (int e = e0 + threadIdx.x; e < e1; e += 256)
        atomicAdd(&lhist[second[e] >> BIN_SHIFT], 1);
    __syncthreads();
    for (int i = threadIdx.x; i < nbins; i += 256)
        ghist[i * gridDim.x + blockIdx.x] = lhist[i];
}

__global__ __launch_bounds__(1024) void scan8_kernel(int* __restrict__ data, int n)
{
    __shared__ int wsum[16], woff[16];
    __shared__ int s_total, s_carry;
    const int tid = threadIdx.x, wave = tid >> 6, lane = tid & 63;
    if (tid == 0) s_carry = 0;
    __syncthreads();
    for (int base = 0; base < n; base += 8192) {
        const int i0 = base + tid * 8;
        int x[8];
#pragma unroll
        for (int k = 0; k < 8; ++k) x[k] = 0;
        if (i0 + 8 <= n) {
            const int4 a = *(const int4*)(data + i0);
            const int4 b = *(const int4*)(data + i0 + 4);
            x[0] = a.x; x[1] = a.y; x[2] = a.z; x[3] = a.w;
            x[4] = b.x; x[5] = b.y; x[6] = b.z; x[7] = b.w;
        } else {
#pragma unroll
            for (int k = 0; k < 8; ++k) if (i0 + k < n) x[k] = data[i0 + k];
        }
        int tot = 0;
#pragma unroll
        for (int k = 0; k < 8; ++k) tot += x[k];
        int v = tot;
#pragma unroll
        for (int off = 1; off < 64; off <<= 1) {
            int t = __shfl_up(v, off, 64);
            if (lane >= off) v += t;
        }
        if (lane == 63) wsum[wave] = v;
        __syncthreads();
        if (wave == 0) {
            int s = (lane < 16) ? wsum[lane] : 0;
#pragma unroll
            for (int off = 1; off < 16; off <<= 1) {
                int t = __shfl_up(s, off, 64);
                if (lane >= off) s += t;
            }
            if (lane < 16) woff[lane] = s - wsum[lane];
            if (lane == 15) s_total = s;
        }
        __syncthreads();
        int pre = s_carry + woff[wave] + (v - tot);
#pragma unroll
        for (int k = 0; k < 8; ++k) {
            if (i0 + k < n) data[i0 + k] = pre;
            pre += x[k];
        }
        __syncthreads();
        if (tid == 0) s_carry += s_total;
        __syncthreads();
    }
}

__global__ __launch_bounds__(256) void scatterC_kernel(
    const int* __restrict__ first, const int* __restrict__ second,
    const int* __restrict__ offs, int* __restrict__ tmp_first,
    int* __restrict__ tmp_sec, int n_edges, int nbins)
{
    __shared__ int lcur[1024];
    for (int i = threadIdx.x; i < nbins; i += 256)
        lcur[i] = offs[i * gridDim.x + blockIdx.x];
    __syncthreads();
    const int per = (n_edges + gridDim.x - 1) / gridDim.x;
    const int e0 = blockIdx.x * per;
    const int e1 = min(e0 + per, n_edges);
    for (int e = e0 + threadIdx.x; e < e1; e += 256) {
        const int s = second[e];
        const int pos = atomicAdd(&lcur[s >> BIN_SHIFT], 1);
        tmp_first[pos] = first[e];
        tmp_sec[pos] = s;
    }
}

__global__ __launch_bounds__(256) void binsortD_kernel(
    const int* __restrict__ tmp_first, const int* __restrict__ tmp_sec,
    const int* __restrict__ offs, int* __restrict__ sfirst,
    int* __restrict__ row_ptr, int n_edges, int n_links, int nbins)
{
    __shared__ int ldeg[128];
    __shared__ int lpre[128];
    __shared__ int lcur[128];
    const int b = blockIdx.x;
    const int tid = threadIdx.x;
    const int lbase = b << BIN_SHIFT;
    const int nl = min(128, n_links - lbase);
    const int eb = offs[b * NSB];
    const int ee = (b + 1 < nbins) ? offs[(b + 1) * NSB] : n_edges;

    if (tid < 128) ldeg[tid] = 0;
    __syncthreads();
    for (int e = eb + tid; e < ee; e += 256)
        atomicAdd(&ldeg[tmp_sec[e] - lbase], 1);
    __syncthreads();
    if (tid < 64) {
        const int d0 = ldeg[tid], d1 = ldeg[64 + tid];
        int p0 = d0, p1 = d1;
#pragma unroll
        for (int off = 1; off < 64; off <<= 1) {
            const int t0 = __shfl_up(p0, off, 64);
            const int t1 = __shfl_up(p1, off, 64);
            if (tid >= off) { p0 += t0; p1 += t1; }
        }
        const int tot0 = __shfl(p0, 63, 64);
        lpre[tid] = p0 - d0;
        lpre[64 + tid] = tot0 + p1 - d1;
    }
    __syncthreads();
    if (tid < nl) row_ptr[lbase + tid] = eb + lpre[tid];
    if (b == nbins - 1 && tid == 0) row_ptr[n_links] = n_edges;
    if (tid < 128) lcur[tid] = lpre[tid];
    __syncthreads();
    for (int e = eb + tid; e < ee; e += 256) {
        const int pos = eb + atomicAdd(&lcur[tmp_sec[e] - lbase], 1);
        sfirst[pos] = tmp_first[e];
    }
    if (b == 0)
        for (int i = tid; i < 64; i += 256) sfirst[n_edges + i] = 0;  // pipeline pad
}

__global__ __launch_bounds__(256) void growfind_kernel(
    const int* __restrict__ gid, int* __restrict__ grow, int n_links, int G)
{
    const int g = blockIdx.x * blockDim.x + threadIdx.x;
    if (g > G) return;
    if (g == G) { grow[G] = n_links; return; }
    int lo = 0, hi = n_links;
    while (lo < hi) {
        const int mid = (lo + hi) >> 1;
        if (gid[mid] < g) lo = mid + 1; else hi = mid;
    }
    grow[g] = lo;
}

// ---------------- P via MFMA (prepped weights, bf16 output) --------------
__global__ __launch_bounds__(256) void p_mfma_kernel(
    const float* __restrict__ state,
    const unsigned short* __restrict__ WtH, const unsigned short* __restrict__ WtL,
    unsigned short* __restrict__ P, int n_links)
{
    const int tid = threadIdx.x;
    const int wave = tid >> 6;
    const int lane = tid & 63;
    const int m = lane & 15;
    const int qd = lane >> 4;

    // B frags: direct 16B loads from prepped [n][k] arrays — zero conversion
    bf16x8 Bh[2][4], Bl[2][4];
#pragma unroll
    for (int ks = 0; ks < 2; ++ks)
#pragma unroll
        for (int jt = 0; jt < 4; ++jt) {
            Bh[ks][jt] = *(const bf16x8*)(WtH + (size_t)(jt * 16 + m) * 64 + ks * 32 + qd * 8);
            Bl[ks][jt] = *(const bf16x8*)(WtL + (size_t)(jt * 16 + m) * 64 + ks * 32 + qd * 8);
        }

    const int ngroups = (n_links + 63) >> 6;
    for (int g = blockIdx.x; g < ngroups; g += gridDim.x) {
        const int base = g * 64 + wave * 16;
        const int l = base + m;
        const bool lv = (l < n_links);
        float xv[16];
        if (lv) {
            const float4* Sr = (const float4*)(state + (size_t)l * D);
            *(float4*)&xv[0]  = Sr[qd * 2];
            *(float4*)&xv[4]  = Sr[qd * 2 + 1];
            *(float4*)&xv[8]  = Sr[8 + qd * 2];
            *(float4*)&xv[12] = Sr[9 + qd * 2];
        } else {
#pragma unroll
            for (int i = 0; i < 16; ++i) xv[i] = 0.0f;
        }
        bf16x8 Ah[2], Al[2];
        split_pack8(&xv[0], &Ah[0], &Al[0]);
        split_pack8(&xv[8], &Ah[1], &Al[1]);
        f32x4 accP[4];
#pragma unroll
        for (int jt = 0; jt < 4; ++jt) {
            accP[jt] = (f32x4){0.f, 0.f, 0.f, 0.f};
#pragma unroll
            for (int ks = 0; ks < 2; ++ks) {
                accP[jt] = __builtin_amdgcn_mfma_f32_16x16x32_bf16(Ah[ks], Bh[ks][jt], accP[jt], 0, 0, 0);
                accP[jt] = __builtin_amdgcn_mfma_f32_16x16x32_bf16(Ah[ks], Bl[ks][jt], accP[jt], 0, 0, 0);
                accP[jt] = __builtin_amdgcn_mfma_f32_16x16x32_bf16(Al[ks], Bh[ks][jt], accP[jt], 0, 0, 0);
            }
        }
#pragma unroll
        for (int r = 0; r < 4; ++r) {
            const int lr = base + qd * 4 + r;
            if (lr < n_links) {
#pragma unroll
                for (int jt = 0; jt < 4; ++jt)
                    P[(size_t)lr * D + jt * 16 + m] =
                        (unsigned short)f2bf_rtne(accP[jt][r]);
            }
        }
    }
}

// ---------------- link-centric fused edge kernel, 3-stage pipeline ----------
// r11 structure (134.6 µs measured) + prepped weights (phase-1 WbH/WbL and
// GT are direct 16B loads — removes ~900 conversion-VALU per wave).
// NOTE: no min-waves clause — (256,5) caused a full spill (r8).
// NOTE: do NOT fuse P/Q production here — r12 measured it at -47 µs/dispatch
// (occupancy step 6->5 waves, LDS conflicts, epilogue tail).
__global__ __launch_bounds__(256) void edge_link_kernel(
    const float* state, const unsigned short* __restrict__ P,
    const int* __restrict__ sfirst, const int* __restrict__ row_ptr,
    const unsigned short* __restrict__ WbH, const unsigned short* __restrict__ WbL,
    const unsigned short* __restrict__ GT,
    const float* __restrict__ b_msg, const float* __restrict__ b_gcn,
    float* S, int n_links)
{
    __shared__ float qt[4][CHUNK * QSTRIDE + 4];
    const int tid = threadIdx.x;
    const int wave = tid >> 6;
    const int lane = tid & 63;
    const int m = lane & 15;
    const int qd = lane >> 4;

    const int l0 = (blockIdx.x * 4 + wave) * CHUNK;
    if (l0 >= n_links) return;
    const int l1 = min(l0 + CHUNK, n_links);
    const int nl = l1 - l0;

    float bmsgC[4];
#pragma unroll
    for (int jt = 0; jt < 4; ++jt) bmsgC[jt] = b_msg[jt * 16 + m];

    // ---- Phase 1: Q-tile from state chunk (split-A x split-B MFMA) ----
    {
        const int l = l0 + m;
        const bool lv = (l < n_links) && (m < CHUNK);
        float xv[16];
        if (lv) {
            const float4* Sr = (const float4*)(state + (size_t)l * D);
            *(float4*)&xv[0]  = Sr[qd * 2];
            *(float4*)&xv[4]  = Sr[qd * 2 + 1];
            *(float4*)&xv[8]  = Sr[8 + qd * 2];
            *(float4*)&xv[12] = Sr[9 + qd * 2];
        } else {
#pragma unroll
            for (int i = 0; i < 16; ++i) xv[i] = 0.0f;
        }
        bf16x8 Ah[2], Al[2];
        split_pack8(&xv[0], &Ah[0], &Al[0]);
        split_pack8(&xv[8], &Ah[1], &Al[1]);
        f32x4 accQ[4];
#pragma unroll
        for (int jt = 0; jt < 4; ++jt) accQ[jt] = (f32x4){0.f, 0.f, 0.f, 0.f};
#pragma unroll
        for (int ks = 0; ks < 2; ++ks)
#pragma unroll
            for (int jt = 0; jt < 4; ++jt) {
                const bf16x8 bh = *(const bf16x8*)(WbH + (size_t)(jt * 16 + m) * 64 + ks * 32 + qd * 8);
                const bf16x8 bl = *(const bf16x8*)(WbL + (size_t)(jt * 16 + m) * 64 + ks * 32 + qd * 8);
                accQ[jt] = __builtin_amdgcn_mfma_f32_16x16x32_bf16(Ah[ks], bh, accQ[jt], 0, 0, 0);
                accQ[jt] = __builtin_amdgcn_mfma_f32_16x16x32_bf16(Ah[ks], bl, accQ[jt], 0, 0, 0);
                accQ[jt] = __builtin_amdgcn_mfma_f32_16x16x32_bf16(Al[ks], bh, accQ[jt], 0, 0, 0);
            }
#pragma unroll
        for (int r = 0; r < 4; ++r) {
            const int row = qd * 4 + r;
            if (row < CHUNK) {
#pragma unroll
                for (int jt = 0; jt < 4; ++jt)
                    qt[wave][row * QSTRIDE + jt * 16 + m] = accQ[jt][r] + bmsgC[jt];
            }
        }
    }

    // ---- W_gcn B-frags: prepped plain bf16, direct 16B loads ----
    bf16x8 Gh[2][4];
#pragma unroll
    for (int ks = 0; ks < 2; ++ks)
#pragma unroll
        for (int jt = 0; jt < 4; ++jt)
            Gh[ks][jt] = *(const bf16x8*)(GT + (size_t)(jt * 16 + m) * 64 + ks * 32 + qd * 8);
    float bias_gcn[4], rb[4];
#pragma unroll
    for (int jt = 0; jt < 4; ++jt) {
        bias_gcn[jt] = b_gcn[jt * 16 + m];
        rb[jt] = fmaxf(bias_gcn[jt], 0.0f);
    }

    // ---- per-chunk row_ptr table in one lane-vector register ----
    const int rpv = row_ptr[l0 + min(lane, nl)];
#define RP(i) __shfl(rpv, (i), 64)

    int li0 = 0;
    while (li0 < nl && RP(li0 + 1) == RP(li0)) {
        S[(size_t)(l0 + li0) * D + lane] = 0.0f;
        ++li0;
    }
    if (li0 >= nl) return;
    int eo0 = RP(li0), ee0 = RP(li0 + 1);

    auto advance = [&](int& li, int& eo, int& ee, bool& v) {
        if (!v) return;
        eo += 16;
        if (eo < ee) return;
        int i = li + 1;
        while (i < nl) {
            const int a = RP(i), b = RP(i + 1);
            if (b > a) { li = i; eo = a; ee = b; return; }
            S[(size_t)(l0 + i) * D + lane] = 0.0f;   // empty link
            ++i;
        }
        v = false;
    };

    int li1 = li0, eo1 = eo0, ee1 = ee0; bool v1 = true;
    advance(li1, eo1, ee1, v1);
    int li2 = li1, eo2 = eo1, ee2 = ee1; bool v2 = v1;
    advance(li2, eo2, ee2, v2);

    const int sf0 = sfirst[eo0 + m];
    int sf1 = sfirst[eo1 + m];
    const unsigned short* Pr0 = P + (size_t)sf0 * D;
    bf16x8 p00 = *(const bf16x8*)(Pr0 + qd * 8);
    bf16x8 p01 = *(const bf16x8*)(Pr0 + 32 + qd * 8);

    float qb[16];
    int qli = -1;
    float rsum[4] = {0.f, 0.f, 0.f, 0.f};

    while (true) {
        const int sf2 = sfirst[eo2 + m];
        const unsigned short* Pr1 = P + (size_t)sf1 * D;
        const bf16x8 p10 = *(const bf16x8*)(Pr1 + qd * 8);
        const bf16x8 p11 = *(const bf16x8*)(Pr1 + 32 + qd * 8);

        if (li0 != qli) {
            qli = li0;
            *(float4*)&qb[0]  = *(float4*)&qt[wave][li0 * QSTRIDE + qd * 8];
            *(float4*)&qb[4]  = *(float4*)&qt[wave][li0 * QSTRIDE + qd * 8 + 4];
            *(float4*)&qb[8]  = *(float4*)&qt[wave][li0 * QSTRIDE + 32 + qd * 8];
            *(float4*)&qb[12] = *(float4*)&qt[wave][li0 * QSTRIDE + 32 + qd * 8 + 4];
        }
        const bool ev = (eo0 + m < ee0);
        float msg[16];
#pragma unroll
        for (int i = 0; i < 8; ++i) {
            msg[i]     = ev ? selu_f(bf2f(p00[i]) + qb[i])     : 0.0f;
            msg[8 + i] = ev ? selu_f(bf2f(p01[i]) + qb[8 + i]) : 0.0f;
        }
        bf16x8 Ah0 = pack8(&msg[0]);
        bf16x8 Ah1 = pack8(&msg[8]);

        f32x4 acc[4];
#pragma unroll
        for (int jt = 0; jt < 4; ++jt) {
            const float b = bias_gcn[jt];
            acc[jt] = (f32x4){b, b, b, b};
            acc[jt] = __builtin_amdgcn_mfma_f32_16x16x32_bf16(Ah0, Gh[0][jt], acc[jt], 0, 0, 0);
            acc[jt] = __builtin_amdgcn_mfma_f32_16x16x32_bf16(Ah1, Gh[1][jt], acc[jt], 0, 0, 0);
        }
#pragma unroll
        for (int jt = 0; jt < 4; ++jt)
#pragma unroll
            for (int r = 0; r < 4; ++r)
                rsum[jt] += fmaxf(acc[jt][r], 0.0f);

        const int over = eo0 + qd * 4 + 4 - ee0;
        const float cnt = (float)max(0, min(4, over));
#pragma unroll
        for (int jt = 0; jt < 4; ++jt)
            rsum[jt] -= rb[jt] * cnt;

        if (eo0 + 16 >= ee0) {   // last tile of link li0
#pragma unroll
            for (int jt = 0; jt < 4; ++jt) {
                rsum[jt] += __shfl_xor(rsum[jt], 16, 64);
                rsum[jt] += __shfl_xor(rsum[jt], 32, 64);
            }
            const float outv = (qd == 0) ? rsum[0] : (qd == 1) ? rsum[1]
                             : (qd == 2) ? rsum[2] : rsum[3];
            S[(size_t)(l0 + li0) * D + lane] = outv;
#pragma unroll
            for (int jt = 0; jt < 4; ++jt) rsum[jt] = 0.0f;
        }

        if (!v1) break;
        li0 = li1; eo0 = eo1; ee0 = ee1;
        li1 = li2; eo1 = eo2; ee1 = ee2; v1 = v2;
        advance(li2, eo2, ee2, v2);
        p00 = p10; p01 = p11;
        sf1 = sf2;
    }
#undef RP
}

// ---------------- readout: parallel segment-sum + tiny MLP ----------------
__global__ __launch_bounds__(256) void gsum8_kernel(
    const float* __restrict__ S, const int* __restrict__ grow,
    float* __restrict__ gemb)
{
    __shared__ float red[4][64];
    const int g = blockIdx.x >> 3;
    const int slice = blockIdx.x & 7;
    const int slot = threadIdx.x >> 6;
    const int j = threadIdx.x & 63;
    const int ls = grow[g], le = grow[g + 1];
    float acc = 0.0f;
    for (int l = ls + slice * 4 + slot; l < le; l += 32)
        acc += S[(size_t)l * D + j];
    red[slot][j] = acc;
    __syncthreads();
    if (slot == 0)
        atomicAdd(&gemb[g * D + j], red[0][j] + red[1][j] + red[2][j] + red[3][j]);
}

__global__ __launch_bounds__(256) void mlp_kernel(
    const float* __restrict__ gemb,
    const float* __restrict__ W_r1, const float* __restrict__ b_r1,
    const float* __restrict__ W_r2, const float* __restrict__ b_r2,
    const float* __restrict__ W_r3, const float* __restrict__ b_r3,
    float* __restrict__ out)
{
    __shared__ float gl[64];
    __shared__ float row1[RU];
    __shared__ float row2[RU];
    __shared__ float fin[4];
    const int g = blockIdx.x;
    const int tid = threadIdx.x;
    const int slot = tid >> 6;
    const int lane = tid & 63;

    if (tid < 64) gl[tid] = gemb[g * D + tid];
    __syncthreads();

    float a1 = b_r1[tid];
#pragma unroll 8
    for (int k = 0; k < 64; ++k) a1 += gl[k] * W_r1[k * RU + tid];
    row1[tid] = selu_f(a1);
    __syncthreads();

    float a2 = b_r2[tid];
#pragma unroll 8
    for (int k = 0; k < RU; ++k) a2 += row1[k] * W_r2[k * RU + tid];
    row2[tid] = selu_f(a2);
    __syncthreads();

    float p = row2[tid] * W_r3[tid];
#pragma unroll
    for (int off = 32; off >= 1; off >>= 1)
        p += __shfl_down(p, off, 64);
    if (lane == 0) fin[slot] = p;
    __syncthreads();
    if (tid == 0)
        out[g] = fin[0] + fin[1] + fin[2] + fin[3] + b_r3[0];
}

extern "C" void kernel_launch(void* const* d_in, const int* in_sizes, int n_in,
                              void* d_out, int out_size, void* d_ws, size_t ws_size,
                              hipStream_t stream)
{
    const float* states_action = (const float*)d_in[0];
    const float* W_msg = (const float*)d_in[1];
    const float* b_msg = (const float*)d_in[2];
    const float* W_gcn = (const float*)d_in[3];
    const float* b_gcn = (const float*)d_in[4];
    const float* W_r1 = (const float*)d_in[5];
    const float* b_r1 = (const float*)d_in[6];
    const float* W_r2 = (const float*)d_in[7];
    const float* b_r2 = (const float*)d_in[8];
    const float* W_r3 = (const float*)d_in[9];
    const float* b_r3 = (const float*)d_in[10];
    const int* gid = (const int*)d_in[11];
    const int* first = (const int*)d_in[12];
    const int* second = (const int*)d_in[13];

    const int n_links = in_sizes[0] / D;     // 100000
    const int n_edges = in_sizes[12];        // 1600000
    const int G = out_size;                  // 256
    const int nbins = (n_links + 127) >> BIN_SHIFT;   // 782

    char* ws2 = (char*)d_ws;
    auto alloc = [&](size_t bytes) {
        char* p = ws2; ws2 += (bytes + 63) & ~(size_t)63; return p;
    };
    float* S = (float*)alloc((size_t)n_links * D * sizeof(float));        // 25.6 MB
    unsigned short* Pb = (unsigned short*)alloc((size_t)n_links * D * 2); // 12.8 MB
    float* gemb = (float*)alloc((size_t)G * D * sizeof(float));
    int* row_ptr = (int*)alloc((size_t)(n_links + 1) * sizeof(int));
    int* grow = (int*)alloc((size_t)(G + 1) * sizeof(int));
    int* ghist = (int*)alloc((size_t)nbins * NSB * sizeof(int));
    int* tmp_first = (int*)alloc((size_t)n_edges * sizeof(int));
    int* tmp_sec = (int*)alloc((size_t)n_edges * sizeof(int));
    int* sfirst = (int*)alloc((size_t)(n_edges + 64) * sizeof(int));
    unsigned short* WtH = (unsigned short*)alloc(64 * 64 * 2);
    unsigned short* WtL = (unsigned short*)alloc(64 * 64 * 2);
    unsigned short* WbH = (unsigned short*)alloc(64 * 64 * 2);
    unsigned short* WbL = (unsigned short*)alloc(64 * 64 * 2);
    unsigned short* GT = (unsigned short*)alloc(64 * 64 * 2);

    // ---- weight prep + atomic-free CSR build ----
    hipMemsetAsync(gemb, 0, (size_t)G * D * sizeof(float), stream);
    w_prep_kernel<<<16, 256, 0, stream>>>(W_msg, W_gcn, WtH, WtL, WbH, WbL, GT);
    histA_kernel<<<NSB, 256, 0, stream>>>(second, ghist, n_edges, nbins);
    scan8_kernel<<<1, 1024, 0, stream>>>(ghist, nbins * NSB);
    scatterC_kernel<<<NSB, 256, 0, stream>>>(first, second, ghist,
                                             tmp_first, tmp_sec, n_edges, nbins);
    binsortD_kernel<<<nbins, 256, 0, stream>>>(tmp_first, tmp_sec, ghist,
                                               sfirst, row_ptr, n_edges, n_links, nbins);
    growfind_kernel<<<2, 256, 0, stream>>>(gid, grow, n_links, G);

    // ---- T = 4 message-passing iterations ----
    const int edge_blocks = (n_links + 4 * CHUNK - 1) / (4 * CHUNK);  // 3125
    const float* state_in = states_action;
    for (int t = 0; t < 4; ++t) {
        p_mfma_kernel<<<782, 256, 0, stream>>>(state_in, WtH, WtL, Pb, n_links);
        edge_link_kernel<<<edge_blocks, 256, 0, stream>>>(state_in, Pb, sfirst, row_ptr,
                                                          WbH, WbL, GT, b_msg, b_gcn,
                                                          S, n_links);
        state_in = S;
    }

    // ---- readout ----
    gsum8_kernel<<<G * 8, 256, 0, stream>>>(S, grow, gemb);
    mlp_kernel<<<G, 256, 0, stream>>>(gemb, W_r1, b_r1, W_r2, b_r2,
                                      W_r3, b_r3, (float*)d_out);
}

// Round 14
// 854.543 us; speedup vs baseline: 1.1578x; 1.0093x over previous
//
#include <hip/hip_runtime.h>
#include <hip/hip_bf16.h>
#include <math.h>

#define D 64
#define RU 256
#define CHUNK 8
#define QSTRIDE 68
#define BIN_SHIFT 7          // 128 links per coarse bin
#define NSB 256              // setup blocks for histA/scatterC

typedef short bf16x8 __attribute__((ext_vector_type(8)));
typedef float f32x4 __attribute__((ext_vector_type(4)));

__device__ __forceinline__ float selu_f(float x) {
    return x > 0.0f ? 1.0507009873554805f * x
                    : 1.7580993408473766f * (__expf(x) - 1.0f);
}

__device__ __forceinline__ short f2bf_rtne(float x) {
    union { float f; unsigned u; } v; v.f = x;
    unsigned r = (v.u + 0x7FFFu + ((v.u >> 16) & 1u)) >> 16;
    return (short)r;
}
__device__ __forceinline__ float bf2f(short s) {
    union { float f; unsigned u; } v; v.u = ((unsigned)(unsigned short)s) << 16;
    return v.f;
}
__device__ __forceinline__ unsigned packpair(float a, float b) {
    float2 p; p.x = a; p.y = b;
    __hip_bfloat162 hb = __float22bfloat162_rn(p);
    return *(unsigned*)&hb;
}

__device__ __forceinline__ bf16x8 pack8(const float* v) {
    union { bf16x8 v; unsigned u[4]; } H;
#pragma unroll
    for (int j = 0; j < 4; ++j) H.u[j] = packpair(v[2 * j], v[2 * j + 1]);
    return H.v;
}

__device__ __forceinline__ void split_pack8(const float* v, bf16x8* hi, bf16x8* lo) {
    union { bf16x8 v; unsigned u[4]; } H, L;
#pragma unroll
    for (int j = 0; j < 4; ++j) {
        float2 p; p.x = v[2 * j]; p.y = v[2 * j + 1];
        __hip_bfloat162 hb = __float22bfloat162_rn(p);
        unsigned hu = *(unsigned*)&hb;
        H.u[j] = hu;
        union { unsigned u; float f; } e, o;
        e.u = hu << 16;
        o.u = hu & 0xffff0000u;
        L.u[j] = packpair(p.x - e.f, p.y - o.f);
    }
    *hi = H.v; *lo = L.v;
}

// ================= atomic-free CSR build (r11, unchanged) =================

__global__ __launch_bounds__(256) void histA_kernel(
    const int* __restrict__ second, int* __restrict__ ghist,
    int n_edges, int nbins)
{
    __shared__ int lhist[1024];
    for (int i = threadIdx.x; i < nbins; i += 256) lhist[i] = 0;
    __syncthreads();
    const int per = (n_edges + gridDim.x - 1) / gridDim.x;
    const int e0 = blockIdx.x * per;
    const int e1 = min(e0 + per, n_edges);
    for (int e = e0 + threadIdx.x; e < e1; e += 256)
        atomicAdd(&lhist[second[e] >> BIN_SHIFT], 1);
    __syncthreads();
    for (int i = threadIdx.x; i < nbins; i += 256)
        ghist[i * gridDim.x + blockIdx.x] = lhist[i];
}

__global__ __launch_bounds__(1024) void scan8_kernel(int* __restrict__ data, int n)
{
    __shared__ int wsum[16], woff[16];
    __shared__ int s_total, s_carry;
    const int tid = threadIdx.x, wave = tid >> 6, lane = tid & 63;
    if (tid == 0) s_carry = 0;
    __syncthreads();
    for (int base = 0; base < n; base += 8192) {
        const int i0 = base + tid * 8;
        int x[8];
#pragma unroll
        for (int k = 0; k < 8; ++k) x[k] = 0;
        if (i0 + 8 <= n) {
            const int4 a = *(const int4*)(data + i0);
            const int4 b = *(const int4*)(data + i0 + 4);
            x[0] = a.x; x[1] = a.y; x[2] = a.z; x[3] = a.w;
            x[4] = b.x; x[5] = b.y; x[6] = b.z; x[7] = b.w;
        } else {
#pragma unroll
            for (int k = 0; k < 8; ++k) if (i0 + k < n) x[k] = data[i0 + k];
        }
        int tot = 0;
#pragma unroll
        for (int k = 0; k < 8; ++k) tot += x[k];
        int v = tot;
#pragma unroll
        for (int off = 1; off < 64; off <<= 1) {
            int t = __shfl_up(v, off, 64);
            if (lane >= off) v += t;
        }
        if (lane == 63) wsum[wave] = v;
        __syncthreads();
        if (wave == 0) {
            int s = (lane < 16) ? wsum[lane] : 0;
#pragma unroll
            for (int off = 1; off < 16; off <<= 1) {
                int t = __shfl_up(s, off, 64);
                if (lane >= off) s += t;
            }
            if (lane < 16) woff[lane] = s - wsum[lane];
            if (lane == 15) s_total = s;
        }
        __syncthreads();
        int pre = s_carry + woff[wave] + (v - tot);
#pragma unroll
        for (int k = 0; k < 8; ++k) {
            if (i0 + k < n) data[i0 + k] = pre;
            pre += x[k];
        }
        __syncthreads();
        if (tid == 0) s_carry += s_total;
        __syncthreads();
    }
}

__global__ __launch_bounds__(256) void scatterC_kernel(
    const int* __restrict__ first, const int* __restrict__ second,
    const int* __restrict__ offs, int* __restrict__ tmp_first,
    int* __restrict__ tmp_sec, int n_edges, int nbins)
{
    __shared__ int lcur[1024];
    for (int i = threadIdx.x; i < nbins; i += 256)
        lcur[i] = offs[i * gridDim.x + blockIdx.x];
    __syncthreads();
    const int per = (n_edges + gridDim.x - 1) / gridDim.x;
    const int e0 = blockIdx.x * per;
    const int e1 = min(e0 + per, n_edges);
    for (int e = e0 + threadIdx.x; e < e1; e += 256) {
        const int s = second[e];
        const int pos = atomicAdd(&lcur[s >> BIN_SHIFT], 1);
        tmp_first[pos] = first[e];
        tmp_sec[pos] = s;
    }
}

__global__ __launch_bounds__(256) void binsortD_kernel(
    const int* __restrict__ tmp_first, const int* __restrict__ tmp_sec,
    const int* __restrict__ offs, int* __restrict__ sfirst,
    int* __restrict__ row_ptr, int n_edges, int n_links, int nbins)
{
    __shared__ int ldeg[128];
    __shared__ int lpre[128];
    __shared__ int lcur[128];
    const int b = blockIdx.x;
    const int tid = threadIdx.x;
    const int lbase = b << BIN_SHIFT;
    const int nl = min(128, n_links - lbase);
    const int eb = offs[b * NSB];
    const int ee = (b + 1 < nbins) ? offs[(b + 1) * NSB] : n_edges;

    if (tid < 128) ldeg[tid] = 0;
    __syncthreads();
    for (int e = eb + tid; e < ee; e += 256)
        atomicAdd(&ldeg[tmp_sec[e] - lbase], 1);
    __syncthreads();
    if (tid < 64) {
        const int d0 = ldeg[tid], d1 = ldeg[64 + tid];
        int p0 = d0, p1 = d1;
#pragma unroll
        for (int off = 1; off < 64; off <<= 1) {
            const int t0 = __shfl_up(p0, off, 64);
            const int t1 = __shfl_up(p1, off, 64);
            if (tid >= off) { p0 += t0; p1 += t1; }
        }
        const int tot0 = __shfl(p0, 63, 64);
        lpre[tid] = p0 - d0;
        lpre[64 + tid] = tot0 + p1 - d1;
    }
    __syncthreads();
    if (tid < nl) row_ptr[lbase + tid] = eb + lpre[tid];
    if (b == nbins - 1 && tid == 0) row_ptr[n_links] = n_edges;
    if (tid < 128) lcur[tid] = lpre[tid];
    __syncthreads();
    for (int e = eb + tid; e < ee; e += 256) {
        const int pos = eb + atomicAdd(&lcur[tmp_sec[e] - lbase], 1);
        sfirst[pos] = tmp_first[e];
    }
    if (b == 0)
        for (int i = tid; i < 64; i += 256) sfirst[n_edges + i] = 0;  // pipeline pad
}

__global__ __launch_bounds__(256) void growfind_kernel(
    const int* __restrict__ gid, int* __restrict__ grow, int n_links, int G)
{
    const int g = blockIdx.x * blockDim.x + threadIdx.x;
    if (g > G) return;
    if (g == G) { grow[G] = n_links; return; }
    int lo = 0, hi = n_links;
    while (lo < hi) {
        const int mid = (lo + hi) >> 1;
        if (gid[mid] < g) lo = mid + 1; else hi = mid;
    }
    grow[g] = lo;
}

// ---------------- P via MFMA (r11: inline split, bf16 output) ---------------
__global__ __launch_bounds__(256) void p_mfma_kernel(
    const float* __restrict__ state, const float* __restrict__ W_msg,
    unsigned short* __restrict__ P, int n_links)
{
    const int tid = threadIdx.x;
    const int wave = tid >> 6;
    const int lane = tid & 63;
    const int m = lane & 15;
    const int qd = lane >> 4;

    bf16x8 Bh[2][4], Bl[2][4];
#pragma unroll
    for (int ks = 0; ks < 2; ++ks)
#pragma unroll
        for (int jt = 0; jt < 4; ++jt) {
            const int nn = jt * 16 + m;
#pragma unroll
            for (int i = 0; i < 8; ++i) {
                const int kk = ks * 32 + qd * 8 + i;
                const float w = W_msg[kk * 64 + nn];
                const short hi = f2bf_rtne(w);
                Bh[ks][jt][i] = hi;
                Bl[ks][jt][i] = f2bf_rtne(w - bf2f(hi));
            }
        }

    const int ngroups = (n_links + 63) >> 6;
    for (int g = blockIdx.x; g < ngroups; g += gridDim.x) {
        const int base = g * 64 + wave * 16;
        const int l = base + m;
        const bool lv = (l < n_links);
        float xv[16];
        if (lv) {
            const float4* Sr = (const float4*)(state + (size_t)l * D);
            *(float4*)&xv[0]  = Sr[qd * 2];
            *(float4*)&xv[4]  = Sr[qd * 2 + 1];
            *(float4*)&xv[8]  = Sr[8 + qd * 2];
            *(float4*)&xv[12] = Sr[9 + qd * 2];
        } else {
#pragma unroll
            for (int i = 0; i < 16; ++i) xv[i] = 0.0f;
        }
        bf16x8 Ah[2], Al[2];
        split_pack8(&xv[0], &Ah[0], &Al[0]);
        split_pack8(&xv[8], &Ah[1], &Al[1]);
        f32x4 accP[4];
#pragma unroll
        for (int jt = 0; jt < 4; ++jt) {
            accP[jt] = (f32x4){0.f, 0.f, 0.f, 0.f};
#pragma unroll
            for (int ks = 0; ks < 2; ++ks) {
                accP[jt] = __builtin_amdgcn_mfma_f32_16x16x32_bf16(Ah[ks], Bh[ks][jt], accP[jt], 0, 0, 0);
                accP[jt] = __builtin_amdgcn_mfma_f32_16x16x32_bf16(Ah[ks], Bl[ks][jt], accP[jt], 0, 0, 0);
                accP[jt] = __builtin_amdgcn_mfma_f32_16x16x32_bf16(Al[ks], Bh[ks][jt], accP[jt], 0, 0, 0);
            }
        }
#pragma unroll
        for (int r = 0; r < 4; ++r) {
            const int lr = base + qd * 4 + r;
            if (lr < n_links) {
#pragma unroll
                for (int jt = 0; jt < 4; ++jt)
                    P[(size_t)lr * D + jt * 16 + m] =
                        (unsigned short)f2bf_rtne(accP[jt][r]);
            }
        }
    }
}

// ---------------- link-centric fused edge kernel, 4-stage pipeline ----------
// r11 structure + deeper prefetch: sfirst issued 3 tiles ahead, P rows issued
// 2 tiles ahead (2 tile-computes of latency cover vs 1 in r11). Register
// offsets: qb held as packed bf16 (-8 VGPR), tail-correction moved into the
// link-close branch (rb recomputed there, -4 VGPR).
// NOTE: no min-waves clause — (256,5) caused a full spill (r8). Target is
// VGPR <= 85 to keep 6 waves/SIMD (r12 showed 88 -> 5 waves regresses).
__global__ __launch_bounds__(256) void edge_link_kernel(
    const float* state, const unsigned short* __restrict__ P,
    const int* __restrict__ sfirst, const int* __restrict__ row_ptr,
    const float* __restrict__ b_msg, const float* __restrict__ W_msg,
    const float* __restrict__ W_gcn, const float* __restrict__ b_gcn,
    float* S, int n_links)
{
    __shared__ float qt[4][CHUNK * QSTRIDE + 4];
    const int tid = threadIdx.x;
    const int wave = tid >> 6;
    const int lane = tid & 63;
    const int m = lane & 15;
    const int qd = lane >> 4;

    const int l0 = (blockIdx.x * 4 + wave) * CHUNK;
    if (l0 >= n_links) return;
    const int l1 = min(l0 + CHUNK, n_links);
    const int nl = l1 - l0;

    float bmsgC[4];
#pragma unroll
    for (int jt = 0; jt < 4; ++jt) bmsgC[jt] = b_msg[jt * 16 + m];

    // ---- Phase 1: Q-tile from state chunk (split-A x split-B MFMA) ----
    {
        const int l = l0 + m;
        const bool lv = (l < n_links) && (m < CHUNK);
        float xv[16];
        if (lv) {
            const float4* Sr = (const float4*)(state + (size_t)l * D);
            *(float4*)&xv[0]  = Sr[qd * 2];
            *(float4*)&xv[4]  = Sr[qd * 2 + 1];
            *(float4*)&xv[8]  = Sr[8 + qd * 2];
            *(float4*)&xv[12] = Sr[9 + qd * 2];
        } else {
#pragma unroll
            for (int i = 0; i < 16; ++i) xv[i] = 0.0f;
        }
        bf16x8 Ah[2], Al[2];
        split_pack8(&xv[0], &Ah[0], &Al[0]);
        split_pack8(&xv[8], &Ah[1], &Al[1]);
        f32x4 accQ[4];
#pragma unroll
        for (int jt = 0; jt < 4; ++jt) accQ[jt] = (f32x4){0.f, 0.f, 0.f, 0.f};
#pragma unroll
        for (int ks = 0; ks < 2; ++ks) {
            bf16x8 WbH[4], WbL[4];
#pragma unroll
            for (int jt = 0; jt < 4; ++jt) {
                const int nn = jt * 16 + m;
#pragma unroll
                for (int i = 0; i < 8; ++i) {
                    const int kk = 64 + ks * 32 + qd * 8 + i;
                    const float w = W_msg[kk * 64 + nn];
                    const short hi = f2bf_rtne(w);
                    WbH[jt][i] = hi;
                    WbL[jt][i] = f2bf_rtne(w - bf2f(hi));
                }
            }
#pragma unroll
            for (int jt = 0; jt < 4; ++jt) {
                accQ[jt] = __builtin_amdgcn_mfma_f32_16x16x32_bf16(Ah[ks], WbH[jt], accQ[jt], 0, 0, 0);
                accQ[jt] = __builtin_amdgcn_mfma_f32_16x16x32_bf16(Ah[ks], WbL[jt], accQ[jt], 0, 0, 0);
                accQ[jt] = __builtin_amdgcn_mfma_f32_16x16x32_bf16(Al[ks], WbH[jt], accQ[jt], 0, 0, 0);
            }
        }
#pragma unroll
        for (int r = 0; r < 4; ++r) {
            const int row = qd * 4 + r;
            if (row < CHUNK) {
#pragma unroll
                for (int jt = 0; jt < 4; ++jt)
                    qt[wave][row * QSTRIDE + jt * 16 + m] = accQ[jt][r] + bmsgC[jt];
            }
        }
    }

    // ---- W_gcn B-frags (inline bf16 conversion, r11) ----
    bf16x8 Gh[2][4];
#pragma unroll
    for (int ks = 0; ks < 2; ++ks)
#pragma unroll
        for (int jt = 0; jt < 4; ++jt) {
            const int nn = jt * 16 + m;
#pragma unroll
            for (int i = 0; i < 8; ++i)
                Gh[ks][jt][i] = f2bf_rtne(W_gcn[(ks * 32 + qd * 8 + i) * 64 + nn]);
        }
    float bias_gcn[4];
#pragma unroll
    for (int jt = 0; jt < 4; ++jt) bias_gcn[jt] = b_gcn[jt * 16 + m];

    // ---- per-chunk row_ptr table in one lane-vector register ----
    const int rpv = row_ptr[l0 + min(lane, nl)];
#define RP(i) __shfl(rpv, (i), 64)

    int li0 = 0;
    while (li0 < nl && RP(li0 + 1) == RP(li0)) {
        S[(size_t)(l0 + li0) * D + lane] = 0.0f;
        ++li0;
    }
    if (li0 >= nl) return;
    int eo0 = RP(li0), ee0 = RP(li0 + 1);

    auto advance = [&](int& li, int& eo, int& ee, bool& v) {
        if (!v) return;
        eo += 16;
        if (eo < ee) return;
        int i = li + 1;
        while (i < nl) {
            const int a = RP(i), b = RP(i + 1);
            if (b > a) { li = i; eo = a; ee = b; return; }
            S[(size_t)(l0 + i) * D + lane] = 0.0f;   // empty link
            ++i;
        }
        v = false;
    };

    int li1 = li0, eo1 = eo0, ee1 = ee0; bool v1 = true;
    advance(li1, eo1, ee1, v1);
    int li2 = li1, eo2 = eo1, ee2 = ee1; bool v2 = v1;
    advance(li2, eo2, ee2, v2);
    int li3 = li2, eo3 = eo2, ee3 = ee2; bool v3 = v2;
    advance(li3, eo3, ee3, v3);

    // prologue loads (sfirst padded; frozen-stage over-reads are in-bounds)
    const int sf0 = sfirst[eo0 + m];
    const int sf1 = sfirst[eo1 + m];
    int sf2 = sfirst[eo2 + m];
    const unsigned short* Pr0 = P + (size_t)sf0 * D;
    bf16x8 p0a = *(const bf16x8*)(Pr0 + qd * 8);
    bf16x8 p0b = *(const bf16x8*)(Pr0 + 32 + qd * 8);
    const unsigned short* Pr1 = P + (size_t)sf1 * D;
    bf16x8 p1a = *(const bf16x8*)(Pr1 + qd * 8);
    bf16x8 p1b = *(const bf16x8*)(Pr1 + 32 + qd * 8);

    unsigned qbu[8];        // Q[l]+b_msg, packed bf16 (8 regs vs 16 fp32)
    int qli = -1;
    float rsum[4] = {0.f, 0.f, 0.f, 0.f};

    while (true) {
        // stage A: sfirst for tile t+3
        const int sf3v = sfirst[eo3 + m];
        // stage B: P rows for tile t+2 (sf2 ready since last iteration)
        const unsigned short* Pr2 = P + (size_t)sf2 * D;
        const bf16x8 p2a = *(const bf16x8*)(Pr2 + qd * 8);
        const bf16x8 p2b = *(const bf16x8*)(Pr2 + 32 + qd * 8);

        // stage C: compute tile t
        if (li0 != qli) {
            qli = li0;
            float4 a0 = *(float4*)&qt[wave][li0 * QSTRIDE + qd * 8];
            float4 a1 = *(float4*)&qt[wave][li0 * QSTRIDE + qd * 8 + 4];
            float4 a2 = *(float4*)&qt[wave][li0 * QSTRIDE + 32 + qd * 8];
            float4 a3 = *(float4*)&qt[wave][li0 * QSTRIDE + 32 + qd * 8 + 4];
            qbu[0] = packpair(a0.x, a0.y); qbu[1] = packpair(a0.z, a0.w);
            qbu[2] = packpair(a1.x, a1.y); qbu[3] = packpair(a1.z, a1.w);
            qbu[4] = packpair(a2.x, a2.y); qbu[5] = packpair(a2.z, a2.w);
            qbu[6] = packpair(a3.x, a3.y); qbu[7] = packpair(a3.z, a3.w);
        }
        const bool ev = (eo0 + m < ee0);
        float msg[16];
#pragma unroll
        for (int j = 0; j < 4; ++j) {
            union { unsigned u; float f; } e, o, e2, o2;
            e.u  = qbu[j] << 16;
            o.u  = qbu[j] & 0xffff0000u;
            e2.u = qbu[4 + j] << 16;
            o2.u = qbu[4 + j] & 0xffff0000u;
            msg[2 * j]         = ev ? selu_f(bf2f(p0a[2 * j])     + e.f)  : 0.0f;
            msg[2 * j + 1]     = ev ? selu_f(bf2f(p0a[2 * j + 1]) + o.f)  : 0.0f;
            msg[8 + 2 * j]     = ev ? selu_f(bf2f(p0b[2 * j])     + e2.f) : 0.0f;
            msg[8 + 2 * j + 1] = ev ? selu_f(bf2f(p0b[2 * j + 1]) + o2.f) : 0.0f;
        }
        bf16x8 Ah0 = pack8(&msg[0]);
        bf16x8 Ah1 = pack8(&msg[8]);

        f32x4 acc[4];
#pragma unroll
        for (int jt = 0; jt < 4; ++jt) {
            const float b = bias_gcn[jt];
            acc[jt] = (f32x4){b, b, b, b};
            acc[jt] = __builtin_amdgcn_mfma_f32_16x16x32_bf16(Ah0, Gh[0][jt], acc[jt], 0, 0, 0);
            acc[jt] = __builtin_amdgcn_mfma_f32_16x16x32_bf16(Ah1, Gh[1][jt], acc[jt], 0, 0, 0);
        }
#pragma unroll
        for (int jt = 0; jt < 4; ++jt)
#pragma unroll
            for (int r = 0; r < 4; ++r)
                rsum[jt] += fmaxf(acc[jt][r], 0.0f);

        if (eo0 + 16 >= ee0) {   // last tile of link li0
            // bias correction: invalid rows contributed exactly relu(b_gcn)
            const int over = eo0 + qd * 4 + 4 - ee0;
            const float cnt = (float)max(0, min(4, over));
#pragma unroll
            for (int jt = 0; jt < 4; ++jt)
                rsum[jt] -= fmaxf(bias_gcn[jt], 0.0f) * cnt;
#pragma unroll
            for (int jt = 0; jt < 4; ++jt) {
                rsum[jt] += __shfl_xor(rsum[jt], 16, 64);
                rsum[jt] += __shfl_xor(rsum[jt], 32, 64);
            }
            const float outv = (qd == 0) ? rsum[0] : (qd == 1) ? rsum[1]
                             : (qd == 2) ? rsum[2] : rsum[3];
            S[(size_t)(l0 + li0) * D + lane] = outv;
#pragma unroll
            for (int jt = 0; jt < 4; ++jt) rsum[jt] = 0.0f;
        }

        if (!v1) break;
        li0 = li1; eo0 = eo1; ee0 = ee1;
        li1 = li2; eo1 = eo2; ee1 = ee2; v1 = v2;
        li2 = li3; eo2 = eo3; ee2 = ee3; v2 = v3;
        advance(li3, eo3, ee3, v3);
        p0a = p1a; p0b = p1b;
        p1a = p2a; p1b = p2b;
        sf2 = sf3v;
    }
#undef RP
}

// ---------------- readout: parallel segment-sum + tiny MLP ----------------
__global__ __launch_bounds__(256) void gsum8_kernel(
    const float* __restrict__ S, const int* __restrict__ grow,
    float* __restrict__ gemb)
{
    __shared__ float red[4][64];
    const int g = blockIdx.x >> 3;
    const int slice = blockIdx.x & 7;
    const int slot = threadIdx.x >> 6;
    const int j = threadIdx.x & 63;
    const int ls = grow[g], le = grow[g + 1];
    float acc = 0.0f;
    for (int l = ls + slice * 4 + slot; l < le; l += 32)
        acc += S[(size_t)l * D + j];
    red[slot][j] = acc;
    __syncthreads();
    if (slot == 0)
        atomicAdd(&gemb[g * D + j], red[0][j] + red[1][j] + red[2][j] + red[3][j]);
}

__global__ __launch_bounds__(256) void mlp_kernel(
    const float* __restrict__ gemb,
    const float* __restrict__ W_r1, const float* __restrict__ b_r1,
    const float* __restrict__ W_r2, const float* __restrict__ b_r2,
    const float* __restrict__ W_r3, const float* __restrict__ b_r3,
    float* __restrict__ out)
{
    __shared__ float gl[64];
    __shared__ float row1[RU];
    __shared__ float row2[RU];
    __shared__ float fin[4];
    const int g = blockIdx.x;
    const int tid = threadIdx.x;
    const int slot = tid >> 6;
    const int lane = tid & 63;

    if (tid < 64) gl[tid] = gemb[g * D + tid];
    __syncthreads();

    float a1 = b_r1[tid];
#pragma unroll 8
    for (int k = 0; k < 64; ++k) a1 += gl[k] * W_r1[k * RU + tid];
    row1[tid] = selu_f(a1);
    __syncthreads();

    float a2 = b_r2[tid];
#pragma unroll 8
    for (int k = 0; k < RU; ++k) a2 += row1[k] * W_r2[k * RU + tid];
    row2[tid] = selu_f(a2);
    __syncthreads();

    float p = row2[tid] * W_r3[tid];
#pragma unroll
    for (int off = 32; off >= 1; off >>= 1)
        p += __shfl_down(p, off, 64);
    if (lane == 0) fin[slot] = p;
    __syncthreads();
    if (tid == 0)
        out[g] = fin[0] + fin[1] + fin[2] + fin[3] + b_r3[0];
}

extern "C" void kernel_launch(void* const* d_in, const int* in_sizes, int n_in,
                              void* d_out, int out_size, void* d_ws, size_t ws_size,
                              hipStream_t stream)
{
    const float* states_action = (const float*)d_in[0];
    const float* W_msg = (const float*)d_in[1];
    const float* b_msg = (const float*)d_in[2];
    const float* W_gcn = (const float*)d_in[3];
    const float* b_gcn = (const float*)d_in[4];
    const float* W_r1 = (const float*)d_in[5];
    const float* b_r1 = (const float*)d_in[6];
    const float* W_r2 = (const float*)d_in[7];
    const float* b_r2 = (const float*)d_in[8];
    const float* W_r3 = (const float*)d_in[9];
    const float* b_r3 = (const float*)d_in[10];
    const int* gid = (const int*)d_in[11];
    const int* first = (const int*)d_in[12];
    const int* second = (const int*)d_in[13];

    const int n_links = in_sizes[0] / D;     // 100000
    const int n_edges = in_sizes[12];        // 1600000
    const int G = out_size;                  // 256
    const int nbins = (n_links + 127) >> BIN_SHIFT;   // 782

    char* ws2 = (char*)d_ws;
    auto alloc = [&](size_t bytes) {
        char* p = ws2; ws2 += (bytes + 63) & ~(size_t)63; return p;
    };
    float* S = (float*)alloc((size_t)n_links * D * sizeof(float));        // 25.6 MB
    unsigned short* Pb = (unsigned short*)alloc((size_t)n_links * D * 2); // 12.8 MB
    float* gemb = (float*)alloc((size_t)G * D * sizeof(float));
    int* row_ptr = (int*)alloc((size_t)(n_links + 1) * sizeof(int));
    int* grow = (int*)alloc((size_t)(G + 1) * sizeof(int));
    int* ghist = (int*)alloc((size_t)nbins * NSB * sizeof(int));
    int* tmp_first = (int*)alloc((size_t)n_edges * sizeof(int));
    int* tmp_sec = (int*)alloc((size_t)n_edges * sizeof(int));
    int* sfirst = (int*)alloc((size_t)(n_edges + 64) * sizeof(int));

    // ---- atomic-free CSR build ----
    hipMemsetAsync(gemb, 0, (size_t)G * D * sizeof(float), stream);
    histA_kernel<<<NSB, 256, 0, stream>>>(second, ghist, n_edges, nbins);
    scan8_kernel<<<1, 1024, 0, stream>>>(ghist, nbins * NSB);
    scatterC_kernel<<<NSB, 256, 0, stream>>>(first, second, ghist,
                                             tmp_first, tmp_sec, n_edges, nbins);
    binsortD_kernel<<<nbins, 256, 0, stream>>>(tmp_first, tmp_sec, ghist,
                                               sfirst, row_ptr, n_edges, n_links, nbins);
    growfind_kernel<<<2, 256, 0, stream>>>(gid, grow, n_links, G);

    // ---- T = 4 message-passing iterations ----
    const int edge_blocks = (n_links + 4 * CHUNK - 1) / (4 * CHUNK);  // 3125
    const float* state_in = states_action;
    for (int t = 0; t < 4; ++t) {
        p_mfma_kernel<<<782, 256, 0, stream>>>(state_in, W_msg, Pb, n_links);
        edge_link_kernel<<<edge_blocks, 256, 0, stream>>>(state_in, Pb, sfirst, row_ptr,
                                                          b_msg, W_msg, W_gcn, b_gcn,
                                                          S, n_links);
        state_in = S;
    }

    // ---- readout ----
    gsum8_kernel<<<G * 8, 256, 0, stream>>>(S, grow, gemb);
    mlp_kernel<<<G, 256, 0, stream>>>(gemb, W_r1, b_r1, W_r2, b_r2,
                                      W_r3, b_r3, (float*)d_out);
}

// Round 15
// 829.343 us; speedup vs baseline: 1.1930x; 1.0304x over previous
//
#include <hip/hip_runtime.h>
#include <hip/hip_bf16.h>
#include <math.h>

#define D 64
#define RU 256
#define CHUNK 8
#define QSTRIDE 68
#define BIN_SHIFT 7          // 128 links per coarse bin
#define NSB 256              // setup blocks for histA/scatterC

typedef short bf16x8 __attribute__((ext_vector_type(8)));
typedef float f32x4 __attribute__((ext_vector_type(4)));

__device__ __forceinline__ float selu_f(float x) {
    return x > 0.0f ? 1.0507009873554805f * x
                    : 1.7580993408473766f * (__expf(x) - 1.0f);
}

__device__ __forceinline__ short f2bf_rtne(float x) {
    union { float f; unsigned u; } v; v.f = x;
    unsigned r = (v.u + 0x7FFFu + ((v.u >> 16) & 1u)) >> 16;
    return (short)r;
}
__device__ __forceinline__ float bf2f(short s) {
    union { float f; unsigned u; } v; v.u = ((unsigned)(unsigned short)s) << 16;
    return v.f;
}
__device__ __forceinline__ unsigned packpair(float a, float b) {
    float2 p; p.x = a; p.y = b;
    __hip_bfloat162 hb = __float22bfloat162_rn(p);
    return *(unsigned*)&hb;
}

__device__ __forceinline__ bf16x8 pack8(const float* v) {
    union { bf16x8 v; unsigned u[4]; } H;
#pragma unroll
    for (int j = 0; j < 4; ++j) H.u[j] = packpair(v[2 * j], v[2 * j + 1]);
    return H.v;
}

// ================= input conversion: fp32 state -> bf16 =================
__global__ __launch_bounds__(256) void s2bf_kernel(
    const float* __restrict__ in, unsigned short* __restrict__ out, int n4)
{
    for (int i = blockIdx.x * 256 + threadIdx.x; i < n4; i += gridDim.x * 256) {
        const float4 v = ((const float4*)in)[i];
        uint2 o;
        o.x = packpair(v.x, v.y);
        o.y = packpair(v.z, v.w);
        ((uint2*)out)[i] = o;
    }
}

// ================= atomic-free CSR build (r11 + packed tmp) =================

__global__ __launch_bounds__(256) void histA_kernel(
    const int* __restrict__ second, int* __restrict__ ghist,
    int n_edges, int nbins)
{
    __shared__ int lhist[1024];
    for (int i = threadIdx.x; i < nbins; i += 256) lhist[i] = 0;
    __syncthreads();
    const int per = (n_edges + gridDim.x - 1) / gridDim.x;
    const int e0 = blockIdx.x * per;
    const int e1 = min(e0 + per, n_edges);
    for (int e = e0 + threadIdx.x; e < e1; e += 256)
        atomicAdd(&lhist[second[e] >> BIN_SHIFT], 1);
    __syncthreads();
    for (int i = threadIdx.x; i < nbins; i += 256)
        ghist[i * gridDim.x + blockIdx.x] = lhist[i];
}

__global__ __launch_bounds__(1024) void scan8_kernel(int* __restrict__ data, int n)
{
    __shared__ int wsum[16], woff[16];
    __shared__ int s_total, s_carry;
    const int tid = threadIdx.x, wave = tid >> 6, lane = tid & 63;
    if (tid == 0) s_carry = 0;
    __syncthreads();
    for (int base = 0; base < n; base += 8192) {
        const int i0 = base + tid * 8;
        int x[8];
#pragma unroll
        for (int k = 0; k < 8; ++k) x[k] = 0;
        if (i0 + 8 <= n) {
            const int4 a = *(const int4*)(data + i0);
            const int4 b = *(const int4*)(data + i0 + 4);
            x[0] = a.x; x[1] = a.y; x[2] = a.z; x[3] = a.w;
            x[4] = b.x; x[5] = b.y; x[6] = b.z; x[7] = b.w;
        } else {
#pragma unroll
            for (int k = 0; k < 8; ++k) if (i0 + k < n) x[k] = data[i0 + k];
        }
        int tot = 0;
#pragma unroll
        for (int k = 0; k < 8; ++k) tot += x[k];
        int v = tot;
#pragma unroll
        for (int off = 1; off < 64; off <<= 1) {
            int t = __shfl_up(v, off, 64);
            if (lane >= off) v += t;
        }
        if (lane == 63) wsum[wave] = v;
        __syncthreads();
        if (wave == 0) {
            int s = (lane < 16) ? wsum[lane] : 0;
#pragma unroll
            for (int off = 1; off < 16; off <<= 1) {
                int t = __shfl_up(s, off, 64);
                if (lane >= off) s += t;
            }
            if (lane < 16) woff[lane] = s - wsum[lane];
            if (lane == 15) s_total = s;
        }
        __syncthreads();
        int pre = s_carry + woff[wave] + (v - tot);
#pragma unroll
        for (int k = 0; k < 8; ++k) {
            if (i0 + k < n) data[i0 + k] = pre;
            pre += x[k];
        }
        __syncthreads();
        if (tid == 0) s_carry += s_total;
        __syncthreads();
    }
}

// packed tmp: bits [0,20) = first, bits [20,27) = second & 127
__global__ __launch_bounds__(256) void scatterC_kernel(
    const int* __restrict__ first, const int* __restrict__ second,
    const int* __restrict__ offs, unsigned* __restrict__ tmp, int n_edges, int nbins)
{
    __shared__ int lcur[1024];
    for (int i = threadIdx.x; i < nbins; i += 256)
        lcur[i] = offs[i * gridDim.x + blockIdx.x];
    __syncthreads();
    const int per = (n_edges + gridDim.x - 1) / gridDim.x;
    const int e0 = blockIdx.x * per;
    const int e1 = min(e0 + per, n_edges);
    for (int e = e0 + threadIdx.x; e < e1; e += 256) {
        const int s = second[e];
        const int pos = atomicAdd(&lcur[s >> BIN_SHIFT], 1);
        tmp[pos] = (unsigned)first[e] | ((unsigned)(s & 127) << 20);
    }
}

__global__ __launch_bounds__(256) void binsortD_kernel(
    const unsigned* __restrict__ tmp, const int* __restrict__ offs,
    int* __restrict__ sfirst, int* __restrict__ row_ptr,
    int n_edges, int n_links, int nbins)
{
    __shared__ int ldeg[128];
    __shared__ int lpre[128];
    __shared__ int lcur[128];
    const int b = blockIdx.x;
    const int tid = threadIdx.x;
    const int lbase = b << BIN_SHIFT;
    const int nl = min(128, n_links - lbase);
    const int eb = offs[b * NSB];
    const int ee = (b + 1 < nbins) ? offs[(b + 1) * NSB] : n_edges;

    if (tid < 128) ldeg[tid] = 0;
    __syncthreads();
    for (int e = eb + tid; e < ee; e += 256)
        atomicAdd(&ldeg[tmp[e] >> 20], 1);
    __syncthreads();
    if (tid < 64) {
        const int d0 = ldeg[tid], d1 = ldeg[64 + tid];
        int p0 = d0, p1 = d1;
#pragma unroll
        for (int off = 1; off < 64; off <<= 1) {
            const int t0 = __shfl_up(p0, off, 64);
            const int t1 = __shfl_up(p1, off, 64);
            if (tid >= off) { p0 += t0; p1 += t1; }
        }
        const int tot0 = __shfl(p0, 63, 64);
        lpre[tid] = p0 - d0;
        lpre[64 + tid] = tot0 + p1 - d1;
    }
    __syncthreads();
    if (tid < nl) row_ptr[lbase + tid] = eb + lpre[tid];
    if (b == nbins - 1 && tid == 0) row_ptr[n_links] = n_edges;
    if (tid < 128) lcur[tid] = lpre[tid];
    __syncthreads();
    for (int e = eb + tid; e < ee; e += 256) {
        const unsigned v = tmp[e];
        const int pos = eb + atomicAdd(&lcur[v >> 20], 1);
        sfirst[pos] = (int)(v & 0xFFFFFu);
    }
    if (b == 0)
        for (int i = tid; i < 64; i += 256) sfirst[n_edges + i] = 0;  // pipeline pad
}

__global__ __launch_bounds__(256) void growfind_kernel(
    const int* __restrict__ gid, int* __restrict__ grow, int n_links, int G)
{
    const int g = blockIdx.x * blockDim.x + threadIdx.x;
    if (g > G) return;
    if (g == G) { grow[G] = n_links; return; }
    int lo = 0, hi = n_links;
    while (lo < hi) {
        const int mid = (lo + hi) >> 1;
        if (gid[mid] < g) lo = mid + 1; else hi = mid;
    }
    grow[g] = lo;
}

// ---------------- P via MFMA: bf16 state A (direct loads), split-B ----------
__global__ __launch_bounds__(256) void p_mfma_kernel(
    const unsigned short* __restrict__ Sb, const float* __restrict__ W_msg,
    unsigned short* __restrict__ P, int n_links)
{
    const int tid = threadIdx.x;
    const int wave = tid >> 6;
    const int lane = tid & 63;
    const int m = lane & 15;
    const int qd = lane >> 4;

    bf16x8 Bh[2][4], Bl[2][4];
#pragma unroll
    for (int ks = 0; ks < 2; ++ks)
#pragma unroll
        for (int jt = 0; jt < 4; ++jt) {
            const int nn = jt * 16 + m;
#pragma unroll
            for (int i = 0; i < 8; ++i) {
                const int kk = ks * 32 + qd * 8 + i;
                const float w = W_msg[kk * 64 + nn];
                const short hi = f2bf_rtne(w);
                Bh[ks][jt][i] = hi;
                Bl[ks][jt][i] = f2bf_rtne(w - bf2f(hi));
            }
        }
    const bf16x8 z = (bf16x8){0, 0, 0, 0, 0, 0, 0, 0};

    const int ngroups = (n_links + 63) >> 6;
    for (int g = blockIdx.x; g < ngroups; g += gridDim.x) {
        const int base = g * 64 + wave * 16;
        const int l = base + m;
        bf16x8 Ah0 = z, Ah1 = z;
        if (l < n_links) {
            Ah0 = *(const bf16x8*)(Sb + (size_t)l * D + qd * 8);
            Ah1 = *(const bf16x8*)(Sb + (size_t)l * D + 32 + qd * 8);
        }
        f32x4 accP[4];
#pragma unroll
        for (int jt = 0; jt < 4; ++jt) {
            accP[jt] = (f32x4){0.f, 0.f, 0.f, 0.f};
            accP[jt] = __builtin_amdgcn_mfma_f32_16x16x32_bf16(Ah0, Bh[0][jt], accP[jt], 0, 0, 0);
            accP[jt] = __builtin_amdgcn_mfma_f32_16x16x32_bf16(Ah0, Bl[0][jt], accP[jt], 0, 0, 0);
            accP[jt] = __builtin_amdgcn_mfma_f32_16x16x32_bf16(Ah1, Bh[1][jt], accP[jt], 0, 0, 0);
            accP[jt] = __builtin_amdgcn_mfma_f32_16x16x32_bf16(Ah1, Bl[1][jt], accP[jt], 0, 0, 0);
        }
#pragma unroll
        for (int r = 0; r < 4; ++r) {
            const int lr = base + qd * 4 + r;
            if (lr < n_links) {
#pragma unroll
                for (int jt = 0; jt < 4; ++jt)
                    P[(size_t)lr * D + jt * 16 + m] =
                        (unsigned short)f2bf_rtne(accP[jt][r]);
            }
        }
    }
}

// ---------------- link-centric fused edge kernel (r11 main loop) ------------
// Phase-1 A = direct bf16 loads from Sb; split-B inline (r11). Main loop is
// r11 verbatim (3-stage pipeline — measured best at 134.6 µs; r12/r13/r14
// variants all regressed). S stored bf16.
// NOTE: no min-waves clause — (256,5) caused a full spill (r8).
__global__ __launch_bounds__(256) void edge_link_kernel(
    unsigned short* __restrict__ Sb, const unsigned short* __restrict__ P,
    const int* __restrict__ sfirst, const int* __restrict__ row_ptr,
    const float* __restrict__ b_msg, const float* __restrict__ W_msg,
    const float* __restrict__ W_gcn, const float* __restrict__ b_gcn,
    int n_links)
{
    __shared__ float qt[4][CHUNK * QSTRIDE + 4];
    const int tid = threadIdx.x;
    const int wave = tid >> 6;
    const int lane = tid & 63;
    const int m = lane & 15;
    const int qd = lane >> 4;

    const int l0 = (blockIdx.x * 4 + wave) * CHUNK;
    if (l0 >= n_links) return;
    const int l1 = min(l0 + CHUNK, n_links);
    const int nl = l1 - l0;

    float bmsgC[4];
#pragma unroll
    for (int jt = 0; jt < 4; ++jt) bmsgC[jt] = b_msg[jt * 16 + m];

    // ---- Phase 1: Q-tile from bf16 state chunk (A direct, split-B) ----
    {
        const bf16x8 z = (bf16x8){0, 0, 0, 0, 0, 0, 0, 0};
        const int l = l0 + m;
        bf16x8 Ah0 = z, Ah1 = z;
        if ((l < n_links) && (m < CHUNK)) {
            Ah0 = *(const bf16x8*)(Sb + (size_t)l * D + qd * 8);
            Ah1 = *(const bf16x8*)(Sb + (size_t)l * D + 32 + qd * 8);
        }
        f32x4 accQ[4];
#pragma unroll
        for (int jt = 0; jt < 4; ++jt) accQ[jt] = (f32x4){0.f, 0.f, 0.f, 0.f};
#pragma unroll
        for (int ks = 0; ks < 2; ++ks) {
            bf16x8 WbH[4], WbL[4];
#pragma unroll
            for (int jt = 0; jt < 4; ++jt) {
                const int nn = jt * 16 + m;
#pragma unroll
                for (int i = 0; i < 8; ++i) {
                    const int kk = 64 + ks * 32 + qd * 8 + i;
                    const float w = W_msg[kk * 64 + nn];
                    const short hi = f2bf_rtne(w);
                    WbH[jt][i] = hi;
                    WbL[jt][i] = f2bf_rtne(w - bf2f(hi));
                }
            }
            const bf16x8 A = ks ? Ah1 : Ah0;
#pragma unroll
            for (int jt = 0; jt < 4; ++jt) {
                accQ[jt] = __builtin_amdgcn_mfma_f32_16x16x32_bf16(A, WbH[jt], accQ[jt], 0, 0, 0);
                accQ[jt] = __builtin_amdgcn_mfma_f32_16x16x32_bf16(A, WbL[jt], accQ[jt], 0, 0, 0);
            }
        }
#pragma unroll
        for (int r = 0; r < 4; ++r) {
            const int row = qd * 4 + r;
            if (row < CHUNK) {
#pragma unroll
                for (int jt = 0; jt < 4; ++jt)
                    qt[wave][row * QSTRIDE + jt * 16 + m] = accQ[jt][r] + bmsgC[jt];
            }
        }
    }

    // ---- W_gcn B-frags (inline bf16 conversion, r11) ----
    bf16x8 Gh[2][4];
#pragma unroll
    for (int ks = 0; ks < 2; ++ks)
#pragma unroll
        for (int jt = 0; jt < 4; ++jt) {
            const int nn = jt * 16 + m;
#pragma unroll
            for (int i = 0; i < 8; ++i)
                Gh[ks][jt][i] = f2bf_rtne(W_gcn[(ks * 32 + qd * 8 + i) * 64 + nn]);
        }
    float bias_gcn[4], rb[4];
#pragma unroll
    for (int jt = 0; jt < 4; ++jt) {
        bias_gcn[jt] = b_gcn[jt * 16 + m];
        rb[jt] = fmaxf(bias_gcn[jt], 0.0f);
    }

    // ---- per-chunk row_ptr table in one lane-vector register ----
    const int rpv = row_ptr[l0 + min(lane, nl)];
#define RP(i) __shfl(rpv, (i), 64)

    int li0 = 0;
    while (li0 < nl && RP(li0 + 1) == RP(li0)) {
        Sb[(size_t)(l0 + li0) * D + lane] = 0;
        ++li0;
    }
    if (li0 >= nl) return;
    int eo0 = RP(li0), ee0 = RP(li0 + 1);

    auto advance = [&](int& li, int& eo, int& ee, bool& v) {
        if (!v) return;
        eo += 16;
        if (eo < ee) return;
        int i = li + 1;
        while (i < nl) {
            const int a = RP(i), b = RP(i + 1);
            if (b > a) { li = i; eo = a; ee = b; return; }
            Sb[(size_t)(l0 + i) * D + lane] = 0;     // empty link
            ++i;
        }
        v = false;
    };

    int li1 = li0, eo1 = eo0, ee1 = ee0; bool v1 = true;
    advance(li1, eo1, ee1, v1);
    int li2 = li1, eo2 = eo1, ee2 = ee1; bool v2 = v1;
    advance(li2, eo2, ee2, v2);

    const int sf0 = sfirst[eo0 + m];
    int sf1 = sfirst[eo1 + m];
    const unsigned short* Pr0 = P + (size_t)sf0 * D;
    bf16x8 p00 = *(const bf16x8*)(Pr0 + qd * 8);
    bf16x8 p01 = *(const bf16x8*)(Pr0 + 32 + qd * 8);

    float qb[16];
    int qli = -1;
    float rsum[4] = {0.f, 0.f, 0.f, 0.f};

    while (true) {
        const int sf2 = sfirst[eo2 + m];
        const unsigned short* Pr1 = P + (size_t)sf1 * D;
        const bf16x8 p10 = *(const bf16x8*)(Pr1 + qd * 8);
        const bf16x8 p11 = *(const bf16x8*)(Pr1 + 32 + qd * 8);

        if (li0 != qli) {
            qli = li0;
            *(float4*)&qb[0]  = *(float4*)&qt[wave][li0 * QSTRIDE + qd * 8];
            *(float4*)&qb[4]  = *(float4*)&qt[wave][li0 * QSTRIDE + qd * 8 + 4];
            *(float4*)&qb[8]  = *(float4*)&qt[wave][li0 * QSTRIDE + 32 + qd * 8];
            *(float4*)&qb[12] = *(float4*)&qt[wave][li0 * QSTRIDE + 32 + qd * 8 + 4];
        }
        const bool ev = (eo0 + m < ee0);
        float msg[16];
#pragma unroll
        for (int i = 0; i < 8; ++i) {
            msg[i]     = ev ? selu_f(bf2f(p00[i]) + qb[i])     : 0.0f;
            msg[8 + i] = ev ? selu_f(bf2f(p01[i]) + qb[8 + i]) : 0.0f;
        }
        bf16x8 Ah0 = pack8(&msg[0]);
        bf16x8 Ah1 = pack8(&msg[8]);

        f32x4 acc[4];
#pragma unroll
        for (int jt = 0; jt < 4; ++jt) {
            const float b = bias_gcn[jt];
            acc[jt] = (f32x4){b, b, b, b};
            acc[jt] = __builtin_amdgcn_mfma_f32_16x16x32_bf16(Ah0, Gh[0][jt], acc[jt], 0, 0, 0);
            acc[jt] = __builtin_amdgcn_mfma_f32_16x16x32_bf16(Ah1, Gh[1][jt], acc[jt], 0, 0, 0);
        }
#pragma unroll
        for (int jt = 0; jt < 4; ++jt)
#pragma unroll
            for (int r = 0; r < 4; ++r)
                rsum[jt] += fmaxf(acc[jt][r], 0.0f);

        const int over = eo0 + qd * 4 + 4 - ee0;
        const float cnt = (float)max(0, min(4, over));
#pragma unroll
        for (int jt = 0; jt < 4; ++jt)
            rsum[jt] -= rb[jt] * cnt;

        if (eo0 + 16 >= ee0) {   // last tile of link li0
#pragma unroll
            for (int jt = 0; jt < 4; ++jt) {
                rsum[jt] += __shfl_xor(rsum[jt], 16, 64);
                rsum[jt] += __shfl_xor(rsum[jt], 32, 64);
            }
            const float outv = (qd == 0) ? rsum[0] : (qd == 1) ? rsum[1]
                             : (qd == 2) ? rsum[2] : rsum[3];
            Sb[(size_t)(l0 + li0) * D + lane] = (unsigned short)f2bf_rtne(outv);
#pragma unroll
            for (int jt = 0; jt < 4; ++jt) rsum[jt] = 0.0f;
        }

        if (!v1) break;
        li0 = li1; eo0 = eo1; ee0 = ee1;
        li1 = li2; eo1 = eo2; ee1 = ee2; v1 = v2;
        advance(li2, eo2, ee2, v2);
        p00 = p10; p01 = p11;
        sf1 = sf2;
    }
#undef RP
}

// ---------------- readout: parallel segment-sum (bf16 S) + tiny MLP ---------
__global__ __launch_bounds__(256) void gsum8_kernel(
    const unsigned short* __restrict__ Sb, const int* __restrict__ grow,
    float* __restrict__ gemb)
{
    __shared__ float red[4][64];
    const int g = blockIdx.x >> 3;
    const int slice = blockIdx.x & 7;
    const int slot = threadIdx.x >> 6;
    const int j = threadIdx.x & 63;
    const int ls = grow[g], le = grow[g + 1];
    float acc = 0.0f;
    for (int l = ls + slice * 4 + slot; l < le; l += 32)
        acc += bf2f((short)Sb[(size_t)l * D + j]);
    red[slot][j] = acc;
    __syncthreads();
    if (slot == 0)
        atomicAdd(&gemb[g * D + j], red[0][j] + red[1][j] + red[2][j] + red[3][j]);
}

__global__ __launch_bounds__(256) void mlp_kernel(
    const float* __restrict__ gemb,
    const float* __restrict__ W_r1, const float* __restrict__ b_r1,
    const float* __restrict__ W_r2, const float* __restrict__ b_r2,
    const float* __restrict__ W_r3, const float* __restrict__ b_r3,
    float* __restrict__ out)
{
    __shared__ float gl[64];
    __shared__ float row1[RU];
    __shared__ float row2[RU];
    __shared__ float fin[4];
    const int g = blockIdx.x;
    const int tid = threadIdx.x;
    const int slot = tid >> 6;
    const int lane = tid & 63;

    if (tid < 64) gl[tid] = gemb[g * D + tid];
    __syncthreads();

    float a1 = b_r1[tid];
#pragma unroll 8
    for (int k = 0; k < 64; ++k) a1 += gl[k] * W_r1[k * RU + tid];
    row1[tid] = selu_f(a1);
    __syncthreads();

    float a2 = b_r2[tid];
#pragma unroll 8
    for (int k = 0; k < RU; ++k) a2 += row1[k] * W_r2[k * RU + tid];
    row2[tid] = selu_f(a2);
    __syncthreads();

    float p = row2[tid] * W_r3[tid];
#pragma unroll
    for (int off = 32; off >= 1; off >>= 1)
        p += __shfl_down(p, off, 64);
    if (lane == 0) fin[slot] = p;
    __syncthreads();
    if (tid == 0)
        out[g] = fin[0] + fin[1] + fin[2] + fin[3] + b_r3[0];
}

extern "C" void kernel_launch(void* const* d_in, const int* in_sizes, int n_in,
                              void* d_out, int out_size, void* d_ws, size_t ws_size,
                              hipStream_t stream)
{
    const float* states_action = (const float*)d_in[0];
    const float* W_msg = (const float*)d_in[1];
    const float* b_msg = (const float*)d_in[2];
    const float* W_gcn = (const float*)d_in[3];
    const float* b_gcn = (const float*)d_in[4];
    const float* W_r1 = (const float*)d_in[5];
    const float* b_r1 = (const float*)d_in[6];
    const float* W_r2 = (const float*)d_in[7];
    const float* b_r2 = (const float*)d_in[8];
    const float* W_r3 = (const float*)d_in[9];
    const float* b_r3 = (const float*)d_in[10];
    const int* gid = (const int*)d_in[11];
    const int* first = (const int*)d_in[12];
    const int* second = (const int*)d_in[13];

    const int n_links = in_sizes[0] / D;     // 100000
    const int n_edges = in_sizes[12];        // 1600000
    const int G = out_size;                  // 256
    const int nbins = (n_links + 127) >> BIN_SHIFT;   // 782

    char* ws2 = (char*)d_ws;
    auto alloc = [&](size_t bytes) {
        char* p = ws2; ws2 += (bytes + 63) & ~(size_t)63; return p;
    };
    unsigned short* Sb = (unsigned short*)alloc((size_t)n_links * D * 2); // 12.8 MB
    unsigned short* Pb = (unsigned short*)alloc((size_t)n_links * D * 2); // 12.8 MB
    float* gemb = (float*)alloc((size_t)G * D * sizeof(float));
    int* row_ptr = (int*)alloc((size_t)(n_links + 1) * sizeof(int));
    int* grow = (int*)alloc((size_t)(G + 1) * sizeof(int));
    int* ghist = (int*)alloc((size_t)nbins * NSB * sizeof(int));
    unsigned* tmp = (unsigned*)alloc((size_t)n_edges * sizeof(unsigned));  // 6.4 MB
    int* sfirst = (int*)alloc((size_t)(n_edges + 64) * sizeof(int));       // 6.4 MB

    // ---- input conversion + atomic-free CSR build ----
    hipMemsetAsync(gemb, 0, (size_t)G * D * sizeof(float), stream);
    s2bf_kernel<<<1024, 256, 0, stream>>>(states_action, Sb, n_links * D / 4);
    histA_kernel<<<NSB, 256, 0, stream>>>(second, ghist, n_edges, nbins);
    scan8_kernel<<<1, 1024, 0, stream>>>(ghist, nbins * NSB);
    scatterC_kernel<<<NSB, 256, 0, stream>>>(first, second, ghist, tmp, n_edges, nbins);
    binsortD_kernel<<<nbins, 256, 0, stream>>>(tmp, ghist, sfirst, row_ptr,
                                               n_edges, n_links, nbins);
    growfind_kernel<<<2, 256, 0, stream>>>(gid, grow, n_links, G);

    // ---- T = 4 message-passing iterations (state lives in Sb, bf16) ----
    const int edge_blocks = (n_links + 4 * CHUNK - 1) / (4 * CHUNK);  // 3125
    for (int t = 0; t < 4; ++t) {
        p_mfma_kernel<<<782, 256, 0, stream>>>(Sb, W_msg, Pb, n_links);
        edge_link_kernel<<<edge_blocks, 256, 0, stream>>>(Sb, Pb, sfirst, row_ptr,
                                                          b_msg, W_msg, W_gcn, b_gcn,
                                                          n_links);
    }

    // ---- readout ----
    gsum8_kernel<<<G * 8, 256, 0, stream>>>(Sb, grow, gemb);
    mlp_kernel<<<G, 256, 0, stream>>>(gemb, W_r1, b_r1, W_r2, b_r2,
                                      W_r3, b_r3, (float*)d_out);
}